// Round 1
// baseline (3883.491 us; speedup 1.0000x reference)
//
#include <hip/hip_runtime.h>
#include <stdint.h>

#define BANDS 32
#define CHN   128
#define NPIX  4096
#define NTOT  16777216          // 32*128*4096
#define GSZ   16384             // 128*128
#define KSQ   6                 // squaring stages (G -> G^64, collapse-guarded)

// ---------------- ws layout (float indices) ----------------
// bytes [0..168): doubles: [0]=sumW, [1..10]=lossF acc, [11..20]=loss acc
#define L_OFF    1024
#define GP_OFF   (L_OFF + NTOT)                  // 32*8*16384 gram partials
#define A0_OFF   (GP_OFF + BANDS*8*GSZ)
#define A1_OFF   (A0_OFF + BANDS*GSZ)
#define U3_OFF   (A1_OFF + BANDS*GSZ)            // 32*128*3
#define VW_OFF   (U3_OFF + BANDS*CHN*3)          // 32*128*8 warm-start basis

// ---------------- init: L = x, sumW reduction ----------------
__global__ __launch_bounds__(256) void k_init(const float* __restrict__ x,
                                              const float* __restrict__ W,
                                              float* __restrict__ ws) {
    int gid = blockIdx.x * 256 + threadIdx.x;       // 2048*256 threads
    const float4* x4 = (const float4*)x;
    const float4* w4 = (const float4*)W;
    float4* L4 = (float4*)(ws + L_OFF);
    float s = 0.f;
#pragma unroll
    for (int i = 0; i < 8; i++) {
        int idx = gid + i * 524288;                 // NTOT/4 = 4194304
        float4 xv = x4[idx];
        float4 wv = w4[idx];
        L4[idx] = xv;
        s += wv.x + wv.y + wv.z + wv.w;
    }
    for (int o = 32; o > 0; o >>= 1) s += __shfl_down(s, o, 64);
    __shared__ float red[4];
    int wid = threadIdx.x >> 6, lane = threadIdx.x & 63;
    if (lane == 0) red[wid] = s;
    __syncthreads();
    if (threadIdx.x == 0) {
        float t = red[0] + red[1] + red[2] + red[3];
        atomicAdd((double*)ws, (double)t);
    }
}

// ---------------- gram: partial G[b] = L L^T, split-K 8 ----------------
__global__ __launch_bounds__(256) void k_gram(float* __restrict__ ws) {
    int band = blockIdx.y, kc = blockIdx.x, tid = threadIdx.x;
    __shared__ __align__(16) float Lt[16][132];     // [kk][c], padded
    const float* Lb = ws + L_OFF + (size_t)band * CHN * NPIX;
    int k0 = kc * 512;
    int ty = tid >> 4, tx = tid & 15;
    float acc[8][8];
#pragma unroll
    for (int i = 0; i < 8; i++)
#pragma unroll
        for (int j = 0; j < 8; j++) acc[i][j] = 0.f;

    int lc = tid >> 1, lk = (tid & 1) * 8;
    for (int t = 0; t < 32; t++) {
        int kb = k0 + t * 16;
        const float* src = Lb + (size_t)lc * NPIX + kb + lk;
        float4 v0 = *(const float4*)(src);
        float4 v1 = *(const float4*)(src + 4);
        __syncthreads();
        Lt[lk + 0][lc] = v0.x; Lt[lk + 1][lc] = v0.y;
        Lt[lk + 2][lc] = v0.z; Lt[lk + 3][lc] = v0.w;
        Lt[lk + 4][lc] = v1.x; Lt[lk + 5][lc] = v1.y;
        Lt[lk + 6][lc] = v1.z; Lt[lk + 7][lc] = v1.w;
        __syncthreads();
#pragma unroll
        for (int kk = 0; kk < 16; kk++) {
            float4 a0 = *(const float4*)&Lt[kk][ty * 8];
            float4 a1 = *(const float4*)&Lt[kk][ty * 8 + 4];
            float4 b0 = *(const float4*)&Lt[kk][tx * 8];
            float4 b1 = *(const float4*)&Lt[kk][tx * 8 + 4];
            float a[8] = {a0.x,a0.y,a0.z,a0.w,a1.x,a1.y,a1.z,a1.w};
            float b[8] = {b0.x,b0.y,b0.z,b0.w,b1.x,b1.y,b1.z,b1.w};
#pragma unroll
            for (int i = 0; i < 8; i++)
#pragma unroll
                for (int j = 0; j < 8; j++) acc[i][j] += a[i] * b[j];
        }
    }
    float* Gp = ws + GP_OFF + (size_t)(band * 8 + kc) * GSZ;
#pragma unroll
    for (int i = 0; i < 8; i++) {
        int row = ty * 8 + i;
        *(float4*)&Gp[row * 128 + tx * 8]     = make_float4(acc[i][0], acc[i][1], acc[i][2], acc[i][3]);
        *(float4*)&Gp[row * 128 + tx * 8 + 4] = make_float4(acc[i][4], acc[i][5], acc[i][6], acc[i][7]);
    }
}

// ---------------- sq: B = (A/||A||_F)^2 with local-stat collapse guard ----------------
// first!=0: input = sum of the 8 gram partials (replaces old k_reduceG).
// Stats (fro^2, trace) of the INPUT are computed locally per block (deterministic,
// identical across blocks/waves); collapse flag is redundant because copy-on-collapse
// preserves the stats (collapsed[j] <=> tr^2 < 3.5*fro2 on the stage-j input).
__global__ __launch_bounds__(256) void k_sq(float* __restrict__ ws, int inOff, int outOff, int first) {
    __shared__ __align__(16) float As[16384];       // 64 KB exactly
    int band = blockIdx.y, rb = blockIdx.x * 32, tid = threadIdx.x;
    float* Bout = ws + outOff + (size_t)band * GSZ;
    float4* As4 = (float4*)As;
    float4* Bout4 = (float4*)Bout;

    // ---- stage full input into LDS (swizzled), summing 8 partials if first
    const float4* Ain4 = first
        ? (const float4*)(ws + GP_OFF + (size_t)band * 8 * GSZ)
        : (const float4*)(ws + inOff + (size_t)band * GSZ);
#pragma unroll
    for (int rep = 0; rep < 16; rep++) {
        int fi4 = rep * 256 + tid;
        int c = fi4 >> 5, g = fi4 & 31;
        float4 v = Ain4[fi4];
        if (first) {
#pragma unroll
            for (int p = 1; p < 8; p++) {
                float4 u = Ain4[p * 4096 + fi4];
                v.x += u.x; v.y += u.y; v.z += u.z; v.w += u.w;
            }
        }
        As4[c * 32 + (g ^ (c >> 2))] = v;
    }
    __syncthreads();

    // ---- local stats scan (each wave scans full matrix; identical per-lane order
    //      across waves -> bitwise-identical results; butterfly -> all lanes)
    int lane = tid & 63;
    float fp = 0.f, tp = 0.f;
#pragma unroll 8
    for (int it = 0; it < 64; it++) {
        int fi4 = it * 64 + lane;
        int c = fi4 >> 5, g = fi4 & 31;
        float4 v = As4[c * 32 + (g ^ (c >> 2))];
        fp += v.x*v.x + v.y*v.y + v.z*v.z + v.w*v.w;
        int e = c - 4 * g;
        if (e >= 0 && e < 4) tp += (&v.x)[e];
    }
#pragma unroll
    for (int o = 1; o < 64; o <<= 1) { fp += __shfl_xor(fp, o, 64); tp += __shfl_xor(tp, o, 64); }
    bool collapsed = (tp * tp < 3.5f * fp);

    if (collapsed) {
        // copy this block's 32 rows out of LDS (unswizzle)
#pragma unroll
        for (int rep = 0; rep < 4; rep++) {
            int l4 = rep * 256 + tid;               // 1024 float4 = 32 rows
            int r = rb + (l4 >> 5), g = l4 & 31;
            Bout4[(size_t)r * 32 + g] = As4[r * 32 + (g ^ (r >> 2))];
        }
        return;
    }

    float s2 = 1.0f / fp;       // scale^2 folded into the output write
    int tyy = tid >> 5, txx = tid & 31;
    int r0 = rb + tyy * 4, c0 = txx * 4;
    int rsh = r0 >> 2, csh = c0 >> 2;
    float acc[4][4];
#pragma unroll
    for (int i = 0; i < 4; i++)
#pragma unroll
        for (int j = 0; j < 4; j++) acc[i][j] = 0.f;
#pragma unroll 4
    for (int g = 0; g < 32; g++) {
        float4 a[4], b[4];
        int ga = g ^ rsh, gb = g ^ csh;
#pragma unroll
        for (int i = 0; i < 4; i++) a[i] = As4[(r0 + i) * 32 + ga];
#pragma unroll
        for (int j = 0; j < 4; j++) b[j] = As4[(c0 + j) * 32 + gb];
#pragma unroll
        for (int i = 0; i < 4; i++)
#pragma unroll
            for (int j = 0; j < 4; j++)
                acc[i][j] += a[i].x*b[j].x + a[i].y*b[j].y + a[i].z*b[j].z + a[i].w*b[j].w;
    }
#pragma unroll
    for (int i = 0; i < 4; i++) {
        int row = r0 + i;
        *(float4*)&Bout[row * 128 + c0] =
            make_float4(acc[i][0]*s2, acc[i][1]*s2, acc[i][2]*s2, acc[i][3]*s2);
    }
}

// ---------------- subspace iteration + Rayleigh-Ritz ----------------
// Jacobi now fully in registers via wave shuffles (was: ~550 serialized volatile-LDS
// round trips = the kernel's fixed-latency elephant).
__global__ __launch_bounds__(256) void k_sub(float* __restrict__ ws, int titer) {
    int band = blockIdx.x, tid = threadIdx.x;
    const float* Ab = ws + A0_OFF + (size_t)band * GSZ;
    __shared__ __align__(16) float VcS[8 * 136];
    __shared__ __align__(16) float WcS[8 * 136];
    __shared__ float LchS[64], invdS[8], B8S[64], E8S[64];
    __shared__ int idx3S[3];

    if (titer == 0) {
        for (int idx = tid; idx < 1024; idx += 256) {
            uint32_t h = (uint32_t)(idx + band * 1024 + 7) * 2654435761u;
            h ^= h >> 15; h *= 0x2c1b3c6du; h ^= h >> 12;
            VcS[(idx >> 7) * 136 + (idx & 127)] = ((float)(h & 0xFFFF) / 32768.0f) - 1.0f;
        }
    } else {
        for (int idx = tid; idx < 1024; idx += 256)
            VcS[(idx >> 7) * 136 + (idx & 127)] = ws[VW_OFF + band * 1024 + idx];
    }
    __syncthreads();

    int c = tid & 127, sq = tid >> 7;           // A*V mapping
    int r8 = tid >> 3, s8 = tid & 7;            // 8x8 mappings (tid<64)
    int steps = (titer == 0) ? 8 : 4;

    for (int step = 0; step <= steps; step++) {
        // ---- W = A * V : thread (c,sq) computes W[c][sq*4 .. sq*4+3].
        {
            const float* V0 = VcS + (sq * 4 + 0) * 136;
            const float* V1 = VcS + (sq * 4 + 1) * 136;
            const float* V2 = VcS + (sq * 4 + 2) * 136;
            const float* V3 = VcS + (sq * 4 + 3) * 136;
            float a0 = 0.f, a1 = 0.f, a2 = 0.f, a3 = 0.f;
#pragma unroll 4
            for (int k = 0; k < 128; k += 4) {
                float g0 = Ab[(k + 0) * 128 + c];
                float g1 = Ab[(k + 1) * 128 + c];
                float g2 = Ab[(k + 2) * 128 + c];
                float g3 = Ab[(k + 3) * 128 + c];
                float4 v0 = *(const float4*)&V0[k];
                float4 v1 = *(const float4*)&V1[k];
                float4 v2 = *(const float4*)&V2[k];
                float4 v3 = *(const float4*)&V3[k];
                a0 += g0 * v0.x + g1 * v0.y + g2 * v0.z + g3 * v0.w;
                a1 += g0 * v1.x + g1 * v1.y + g2 * v1.z + g3 * v1.w;
                a2 += g0 * v2.x + g1 * v2.y + g2 * v2.z + g3 * v2.w;
                a3 += g0 * v3.x + g1 * v3.y + g2 * v3.z + g3 * v3.w;
            }
            WcS[(sq * 4 + 0) * 136 + c] = a0;
            WcS[(sq * 4 + 1) * 136 + c] = a1;
            WcS[(sq * 4 + 2) * 136 + c] = a2;
            WcS[(sq * 4 + 3) * 136 + c] = a3;
        }
        __syncthreads();
        if (step == steps) break;

        // ---- CholQR: M = W^T W (wave 0), Cholesky in registers via shuffles
        if (tid < 64) {
            const float* wr = WcS + r8 * 136;
            const float* wc = WcS + s8 * 136;
            float m = 0.f;
#pragma unroll 8
            for (int k = 0; k < 128; k += 4) {
                float4 p = *(const float4*)&wr[k];
                float4 q = *(const float4*)&wc[k];
                m += p.x * q.x + p.y * q.y + p.z * q.z + p.w * q.w;
            }
            float t = (r8 == s8) ? m : 0.f;
#pragma unroll
            for (int o = 1; o < 64; o <<= 1) t += __shfl_xor(t, o, 64);
            float eps = 1e-12f * t + 1e-35f;
            float v = m;
#pragma unroll
            for (int j = 0; j < 8; j++) {
                float dj = __shfl(v, j * 9, 64);
                dj = fmaxf(dj, eps);
                float lj = sqrtf(dj);
                float inv = 1.f / lj;
                if (s8 == j) v = (r8 == j) ? lj : (r8 > j ? v * inv : v);
                float Lr = __shfl(v, r8 * 8 + j, 64);
                float Ls = __shfl(v, s8 * 8 + j, 64);
                if (r8 > j && s8 > j) v -= Lr * Ls;
                if (tid == j) invdS[j] = inv;
            }
            LchS[tid] = v;
        }
        __syncthreads();
        // ---- backsolve V = W L^-T (rows in parallel, tid<128)
        if (tid < 128) {
            float w[8], vv[8];
#pragma unroll
            for (int s = 0; s < 8; s++) w[s] = WcS[s * 136 + tid];
#pragma unroll
            for (int s = 0; s < 8; s++) {
                float t2 = w[s];
                for (int j = 0; j < s; j++) t2 -= vv[j] * LchS[s * 8 + j];
                vv[s] = t2 * invdS[s];
                VcS[s * 136 + tid] = vv[s];
            }
        }
        __syncthreads();
    }

    // ---- Rayleigh-Ritz + symmetrize + Jacobi, all in wave-0 registers
    if (tid < 64) {
        const float* vr = VcS + r8 * 136;
        const float* wc = WcS + s8 * 136;
        float m = 0.f;
#pragma unroll 8
        for (int k = 0; k < 128; k += 4) {
            float4 p = *(const float4*)&vr[k];
            float4 q = *(const float4*)&wc[k];
            m += p.x * q.x + p.y * q.y + p.z * q.z + p.w * q.w;
        }
        float mT = __shfl(m, s8 * 8 + r8, 64);      // symmetrize via shuffle
        float b = 0.5f * (m + mT);
        float e = (r8 == s8) ? 1.f : 0.f;

        for (int sweep = 0; sweep < 6; sweep++) {
            for (int rd = 0; rd < 7; rd++) {
                int pr = (r8 == 7) ? rd : ((r8 == rd) ? 7 : (2 * rd + 7 - r8) % 7);
                int pc = (s8 == 7) ? rd : ((s8 == rd) ? 7 : (2 * rd + 7 - s8) % 7);
                int P = min(r8, pr), Q = max(r8, pr);
                int Pc = min(s8, pc), Qc = max(s8, pc);
                float app = __shfl(b, P * 9, 64);
                float aqq = __shfl(b, Q * 9, 64);
                float apq = __shfl(b, P * 8 + Q, 64);
                float cR, sR;
                if (fabsf(apq) < 1e-28f) { cR = 1.f; sR = 0.f; }
                else {
                    float tau = (aqq - app) / (2.f * apq);
                    float tt = ((tau >= 0.f) ? 1.f : -1.f) / (fabsf(tau) + sqrtf(1.f + tau * tau));
                    cR = rsqrtf(1.f + tt * tt); sR = tt * cR;
                }
                float ap2 = __shfl(b, Pc * 9, 64);
                float aq2 = __shfl(b, Qc * 9, 64);
                float apq2 = __shfl(b, Pc * 8 + Qc, 64);
                float cC, sC;
                if (fabsf(apq2) < 1e-28f) { cC = 1.f; sC = 0.f; }
                else {
                    float tau = (aq2 - ap2) / (2.f * apq2);
                    float tt = ((tau >= 0.f) ? 1.f : -1.f) / (fabsf(tau) + sqrtf(1.f + tau * tau));
                    cC = rsqrtf(1.f + tt * tt); sC = tt * cC;
                }
                // row update: B <- J^T B
                float tv = __shfl(b, pr * 8 + s8, 64);
                float bn = (r8 < pr) ? (cR * b - sR * tv) : (sR * tv + cR * b);
                // col update on row-updated B: B <- B J
                float t2 = __shfl(bn, r8 * 8 + pc, 64);
                b = (s8 < pc) ? (cC * bn - sC * t2) : (sC * t2 + cC * bn);
                // E <- E J
                float e2 = __shfl(e, r8 * 8 + pc, 64);
                e = (s8 < pc) ? (cC * e - sC * e2) : (sC * e2 + cC * e);
            }
        }
        B8S[tid] = b;
        E8S[tid] = e;
        if (tid == 0) {
            int used = 0;
            for (int r = 0; r < 3; r++) {
                int best = 0; float bv = -1e38f;
                for (int s = 0; s < 8; s++)
                    if (!(used & (1 << s)) && B8S[s * 9] > bv) { bv = B8S[s * 9]; best = s; }
                used |= 1 << best;
                idx3S[r] = best;
            }
        }
    }
    __syncthreads();

    // ---- U = V * E[:, idx3], warm-start save
    if (tid < 128) {
        float e[3][8];
#pragma unroll
        for (int r = 0; r < 3; r++)
#pragma unroll
            for (int s = 0; s < 8; s++) e[r][s] = E8S[s * 8 + idx3S[r]];
        float vcl[8];
#pragma unroll
        for (int s = 0; s < 8; s++) vcl[s] = VcS[s * 136 + tid];
#pragma unroll
        for (int r = 0; r < 3; r++) {
            float u = 0.f;
#pragma unroll
            for (int s = 0; s < 8; s++) u += vcl[s] * e[r][s];
            ws[U3_OFF + band * 384 + tid * 3 + r] = u;
        }
#pragma unroll
        for (int s = 0; s < 8; s++) ws[VW_OFF + band * 1024 + s * 128 + tid] = vcl[s];
    }
}

// ---------------- fused: utl = U^T L (phase 1, LDS) + UV/losses/L_new (phase 2) ----------------
__global__ __launch_bounds__(256) void k_upd(const float* __restrict__ x,
                                             const float* __restrict__ W,
                                             const float* __restrict__ xg,
                                             float* __restrict__ out,
                                             float* __restrict__ ws,
                                             float alphapow, int writeUV, int titer) {
    int band = blockIdx.y, xc = blockIdx.x, tid = threadIdx.x;
    int w = tid >> 6, lane = tid & 63;
    int n0 = xc * 256, p4 = lane * 4;
    __shared__ float Us[128][4];
    __shared__ __align__(16) float up[12][260];   // per-wave utl partials [w*3+r][px]
    __shared__ __align__(16) float um[3][260];    // reduced utl
    __shared__ float red[16];

    if (tid < 128) {
        Us[tid][0] = ws[U3_OFF + band * 384 + tid * 3 + 0];
        Us[tid][1] = ws[U3_OFF + band * 384 + tid * 3 + 1];
        Us[tid][2] = ws[U3_OFF + band * 384 + tid * 3 + 2];
    }
    __syncthreads();

    // ---- phase 1: utl[r][p] = sum_c U[c][r] * L[c][p]
    const float* Lb = ws + L_OFF + (size_t)band * CHN * NPIX;
    float4 a0 = make_float4(0.f,0.f,0.f,0.f), a1 = a0, a2 = a0;
    for (int cg = 0; cg < 32; cg++) {
        int c = cg * 4 + w;
        float4 lv = *(const float4*)(Lb + (size_t)c * NPIX + n0 + p4);
        float u0 = Us[c][0], u1 = Us[c][1], u2 = Us[c][2];
        a0.x += u0 * lv.x; a0.y += u0 * lv.y; a0.z += u0 * lv.z; a0.w += u0 * lv.w;
        a1.x += u1 * lv.x; a1.y += u1 * lv.y; a1.z += u1 * lv.z; a1.w += u1 * lv.w;
        a2.x += u2 * lv.x; a2.y += u2 * lv.y; a2.z += u2 * lv.z; a2.w += u2 * lv.w;
    }
    *(float4*)&up[w * 3 + 0][p4] = a0;
    *(float4*)&up[w * 3 + 1][p4] = a1;
    *(float4*)&up[w * 3 + 2][p4] = a2;
    __syncthreads();
    if (tid < 192) {
        int r = tid >> 6, l = (tid & 63) * 4;
        float4 s0 = *(float4*)&up[r][l];
        float4 s1 = *(float4*)&up[3 + r][l];
        float4 s2 = *(float4*)&up[6 + r][l];
        float4 s3 = *(float4*)&up[9 + r][l];
        *(float4*)&um[r][l] = make_float4(s0.x + s1.x + s2.x + s3.x,
                                          s0.y + s1.y + s2.y + s3.y,
                                          s0.z + s1.z + s2.z + s3.z,
                                          s0.w + s1.w + s2.w + s3.w);
    }
    __syncthreads();

    // ---- phase 2: stream x/W/xg, compute UV, losses, L_new (and out at t=9)
    double sw = *(const double*)ws;
    float rho = 0.5f * (float)(sw / (double)NTOT) * alphapow;
    float4 t0 = *(float4*)&um[0][p4];
    float4 t1 = *(float4*)&um[1][p4];
    float4 t2 = *(float4*)&um[2][p4];
    float lf = 0.f, ll = 0.f;
    size_t base = (size_t)band * CHN * NPIX + n0 + p4;
    float* Lp = ws + L_OFF;
#pragma unroll 2
    for (int cg = 0; cg < 32; cg++) {
        int c = cg * 4 + w;
        size_t idx = base + (size_t)c * NPIX;
        float4 xv = *(const float4*)(x + idx);
        float4 wv = *(const float4*)(W + idx);
        float4 gv = *(const float4*)(xg + idx);
        float u0 = Us[c][0], u1 = Us[c][1], u2 = Us[c][2];
        float4 uv, ln;
        uv.x = u0 * t0.x + u1 * t1.x + u2 * t2.x;
        uv.y = u0 * t0.y + u1 * t1.y + u2 * t2.y;
        uv.z = u0 * t0.z + u1 * t1.z + u2 * t2.z;
        uv.w = u0 * t0.w + u1 * t1.w + u2 * t2.w;
        float dx0 = uv.x - xv.x, dx1 = uv.y - xv.y, dx2 = uv.z - xv.z, dx3 = uv.w - xv.w;
        lf += wv.x * dx0 * dx0 + wv.y * dx1 * dx1 + wv.z * dx2 * dx2 + wv.w * dx3 * dx3;
        float g0 = uv.x - gv.x, g1 = uv.y - gv.y, g2 = uv.z - gv.z, g3 = uv.w - gv.w;
        ll += g0 * g0 + g1 * g1 + g2 * g2 + g3 * g3;
        ln.x = xv.x + (rho / (wv.x + rho)) * dx0;
        ln.y = xv.y + (rho / (wv.y + rho)) * dx1;
        ln.z = xv.z + (rho / (wv.z + rho)) * dx2;
        ln.w = xv.w + (rho / (wv.w + rho)) * dx3;
        *(float4*)(Lp + idx) = ln;
        if (writeUV) *(float4*)(out + idx) = uv;
    }
    for (int o = 32; o > 0; o >>= 1) { lf += __shfl_down(lf, o, 64); ll += __shfl_down(ll, o, 64); }
    if (lane == 0) { red[w] = lf; red[8 + w] = ll; }
    __syncthreads();
    if (tid == 0) {
        float a = red[0] + red[1] + red[2] + red[3];
        float b = red[8] + red[9] + red[10] + red[11];
        atomicAdd((double*)ws + 1 + titer,  (double)a);
        atomicAdd((double*)ws + 11 + titer, (double)b);
    }
}

// ---------------- finalize losses ----------------
__global__ void k_final(float* __restrict__ out, const float* __restrict__ ws) {
    int tid = threadIdx.x;
    const double* d = (const double*)ws;
    if (tid < 10)       out[NTOT + tid] = (float)(d[1 + tid] / (double)NTOT);
    else if (tid < 20)  out[NTOT + tid] = (float)(d[11 + (tid - 10)] / (double)NTOT);
}

extern "C" void kernel_launch(void* const* d_in, const int* in_sizes, int n_in,
                              void* d_out, int out_size, void* d_ws, size_t ws_size,
                              hipStream_t stream) {
    const float* x  = (const float*)d_in[0];
    const float* W  = (const float*)d_in[1];
    const float* xg = (const float*)d_in[2];
    float* out = (float*)d_out;
    float* ws = (float*)d_ws;

    hipMemsetAsync(d_ws, 0, 4096, stream);   // zero scalar/accumulator block
    k_init<<<2048, 256, 0, stream>>>(x, W, ws);

    float ap = 1.0f;
    for (int t = 0; t < 10; t++) {
        k_gram<<<dim3(8, 32), 256, 0, stream>>>(ws);
        for (int j = 0; j < KSQ; j++) {
            // stage0: GP(sum of 8) -> A1; then A1->A0->A1->A0->A1->A0 (final in A0)
            int inOff  = (j & 1) ? A1_OFF : A0_OFF;   // ignored when j==0
            int outOff = (j & 1) ? A0_OFF : A1_OFF;
            k_sq<<<dim3(4, 32), 256, 0, stream>>>(ws, inOff, outOff, (j == 0) ? 1 : 0);
        }
        k_sub<<<32, 256, 0, stream>>>(ws, t);
        k_upd<<<dim3(16, 32), 256, 0, stream>>>(x, W, xg, out, ws, ap, (t == 9) ? 1 : 0, t);
        ap *= 1.05f;
    }
    k_final<<<1, 64, 0, stream>>>(out, ws);
}

// Round 2
// 2718.956 us; speedup vs baseline: 1.4283x; 1.4283x over previous
//
#include <hip/hip_runtime.h>
#include <stdint.h>

#define BANDS 32
#define CHN   128
#define NPIX  4096
#define NTOT  16777216          // 32*128*4096
#define GSZ   16384             // 128*128
#define KSQ   6                 // squaring stages (G -> G^64, collapse-guarded)

// ---------------- ws layout (float indices) ----------------
// bytes [0..168): doubles: [0]=sumW, [1..10]=lossF acc, [11..20]=loss acc
#define L_OFF    1024
#define GP_OFF   (L_OFF + NTOT)                  // 32*8*16384 gram partials
#define A0_OFF   (GP_OFF + BANDS*8*GSZ)
#define A1_OFF   (A0_OFF + BANDS*GSZ)
#define U3_OFF   (A1_OFF + BANDS*GSZ)            // 32*128*3
#define VW_OFF   (U3_OFF + BANDS*CHN*3)          // 32*128*8 warm-start basis

typedef short s16x8 __attribute__((ext_vector_type(8)));
typedef float f32x4 __attribute__((ext_vector_type(4)));

__device__ __forceinline__ unsigned short bf16rn(float x) {
    uint32_t u = __float_as_uint(x);
    u += 0x7FFFu + ((u >> 16) & 1u);
    return (unsigned short)(u >> 16);
}
__device__ __forceinline__ float bf16tof(unsigned short h) {
    return __uint_as_float((uint32_t)h << 16);
}

// ---------------- init: L = x, sumW reduction ----------------
__global__ __launch_bounds__(256) void k_init(const float* __restrict__ x,
                                              const float* __restrict__ W,
                                              float* __restrict__ ws) {
    int gid = blockIdx.x * 256 + threadIdx.x;       // 2048*256 threads
    const float4* x4 = (const float4*)x;
    const float4* w4 = (const float4*)W;
    float4* L4 = (float4*)(ws + L_OFF);
    float s = 0.f;
#pragma unroll
    for (int i = 0; i < 8; i++) {
        int idx = gid + i * 524288;                 // NTOT/4 = 4194304
        float4 xv = x4[idx];
        float4 wv = w4[idx];
        L4[idx] = xv;
        s += wv.x + wv.y + wv.z + wv.w;
    }
    for (int o = 32; o > 0; o >>= 1) s += __shfl_down(s, o, 64);
    __shared__ float red[4];
    int wid = threadIdx.x >> 6, lane = threadIdx.x & 63;
    if (lane == 0) red[wid] = s;
    __syncthreads();
    if (threadIdx.x == 0) {
        float t = red[0] + red[1] + red[2] + red[3];
        atomicAdd((double*)ws, (double)t);
    }
}

// ---------------- gram: partial G[b] = L L^T via bf16x2-split MFMA ----------------
// L = H + E (H=bf16rn(L), E=bf16rn(L-H)); G ~= H H^T + H E^T + E H^T (lo*lo dropped,
// ~2^-18 relative). Both operands are rows of the same matrix with the same k index,
// so any internal operand k-permutation cancels; C/D row/col swap only transposes the
// symmetric G. 4 waves, each computes a 64x64 quadrant as 4x4 tiles of 16x16x32 MFMA.
__global__ __launch_bounds__(256) void k_gram(float* __restrict__ ws) {
    int band = blockIdx.y, kc = blockIdx.x, tid = threadIdx.x;
    __shared__ __align__(16) unsigned short Hs[8192];   // 128x64 bf16 hi, XOR-swizzled
    __shared__ __align__(16) unsigned short Lo[8192];   // lo part
    const float* Lb = ws + L_OFF + (size_t)band * CHN * NPIX;
    int k0 = kc * 512;
    int lane = tid & 63, wv = tid >> 6;
    int wr = (wv >> 1) * 64, wcb = (wv & 1) * 64;
    int l15 = lane & 15, l4g = lane >> 4;

    f32x4 acc[4][4];
#pragma unroll
    for (int m = 0; m < 4; m++)
#pragma unroll
        for (int n = 0; n < 4; n++) acc[m][n] = (f32x4){0.f, 0.f, 0.f, 0.f};

    int srow = tid >> 3, scol = (tid & 7) * 8;          // staging map: 32 rows/pass, 8px chunks

    float4 pre[8];                                       // register prefetch (T14)
#pragma unroll
    for (int p = 0; p < 4; p++) {
        const float* src = Lb + (size_t)(srow + p * 32) * NPIX + k0 + scol;
        pre[2 * p]     = *(const float4*)src;
        pre[2 * p + 1] = *(const float4*)(src + 4);
    }
#pragma unroll 1
    for (int t = 0; t < 8; t++) {                        // 8 K-tiles of 64 px
        // ---- convert + write LDS (uses pre = tile t)
#pragma unroll
        for (int p = 0; p < 4; p++) {
            int row = srow + p * 32;
            float vv[8] = {pre[2*p].x, pre[2*p].y, pre[2*p].z, pre[2*p].w,
                           pre[2*p+1].x, pre[2*p+1].y, pre[2*p+1].z, pre[2*p+1].w};
            s16x8 hv, lv;
#pragma unroll
            for (int e = 0; e < 8; e++) {
                unsigned short h = bf16rn(vv[e]);
                float r = vv[e] - bf16tof(h);
                hv[e] = (short)h;
                lv[e] = (short)bf16rn(r);
            }
            int off = row * 128 + ((scol * 2) ^ ((row & 7) << 4));
            *(s16x8*)((char*)Hs + off) = hv;
            *(s16x8*)((char*)Lo + off) = lv;
        }
        __syncthreads();
        // ---- prefetch tile t+1 (overlaps MFMA below)
        if (t < 7) {
            int kn = k0 + (t + 1) * 64;
#pragma unroll
            for (int p = 0; p < 4; p++) {
                const float* src = Lb + (size_t)(srow + p * 32) * NPIX + kn + scol;
                pre[2 * p]     = *(const float4*)src;
                pre[2 * p + 1] = *(const float4*)(src + 4);
            }
        }
        // ---- 2 K-steps of 32
#pragma unroll
        for (int ks = 0; ks < 2; ks++) {
            int kb2 = ks * 64 + l4g * 16;                // byte offset of this lane's k-group
            s16x8 Ah[4], Al[4], Bh[4], Bl[4];
#pragma unroll
            for (int m = 0; m < 4; m++) {
                int row = wr + m * 16 + l15;
                int off = row * 128 + (kb2 ^ ((row & 7) << 4));
                Ah[m] = *(const s16x8*)((const char*)Hs + off);
                Al[m] = *(const s16x8*)((const char*)Lo + off);
            }
#pragma unroll
            for (int n = 0; n < 4; n++) {
                int row = wcb + n * 16 + l15;
                int off = row * 128 + (kb2 ^ ((row & 7) << 4));
                Bh[n] = *(const s16x8*)((const char*)Hs + off);
                Bl[n] = *(const s16x8*)((const char*)Lo + off);
            }
#pragma unroll
            for (int m = 0; m < 4; m++)
#pragma unroll
                for (int n = 0; n < 4; n++) {
                    acc[m][n] = __builtin_amdgcn_mfma_f32_16x16x32_bf16(Ah[m], Bh[n], acc[m][n], 0, 0, 0);
                    acc[m][n] = __builtin_amdgcn_mfma_f32_16x16x32_bf16(Ah[m], Bl[n], acc[m][n], 0, 0, 0);
                    acc[m][n] = __builtin_amdgcn_mfma_f32_16x16x32_bf16(Al[m], Bh[n], acc[m][n], 0, 0, 0);
                }
        }
        __syncthreads();
    }
    // ---- write partial G (layout unchanged for downstream consumers)
    float* Gp = ws + GP_OFF + (size_t)(band * 8 + kc) * GSZ;
#pragma unroll
    for (int m = 0; m < 4; m++)
#pragma unroll
        for (int n = 0; n < 4; n++) {
            int row0 = wr + m * 16 + l4g * 4;
            int col  = wcb + n * 16 + l15;
#pragma unroll
            for (int r = 0; r < 4; r++)
                Gp[(row0 + r) * 128 + col] = acc[m][n][r];
        }
}

// ---------------- sq: B = (A/||A||_F)^2 with local-stat collapse guard ----------------
// first!=0: input = sum of the 8 gram partials. Stats computed locally, wave-split
// (fixed per-wave partition + fixed combine order => identical across blocks).
__global__ __launch_bounds__(256) void k_sq(float* __restrict__ ws, int inOff, int outOff, int first) {
    __shared__ __align__(16) float As[16384];       // 64 KB
    __shared__ float redS[8];
    int band = blockIdx.y, rb = blockIdx.x * 32, tid = threadIdx.x;
    float* Bout = ws + outOff + (size_t)band * GSZ;
    float4* As4 = (float4*)As;
    float4* Bout4 = (float4*)Bout;

    const float4* Ain4 = first
        ? (const float4*)(ws + GP_OFF + (size_t)band * 8 * GSZ)
        : (const float4*)(ws + inOff + (size_t)band * GSZ);
#pragma unroll
    for (int rep = 0; rep < 16; rep++) {
        int fi4 = rep * 256 + tid;
        int c = fi4 >> 5, g = fi4 & 31;
        float4 v = Ain4[fi4];
        if (first) {
#pragma unroll
            for (int p = 1; p < 8; p++) {
                float4 u = Ain4[p * 4096 + fi4];
                v.x += u.x; v.y += u.y; v.z += u.z; v.w += u.w;
            }
        }
        As4[c * 32 + (g ^ (c >> 2))] = v;
    }
    __syncthreads();

    // ---- stats: each wave scans 1/4 (fixed partition), fixed-order combine
    int lane = tid & 63, wv = tid >> 6;
    float fp = 0.f, tp = 0.f;
#pragma unroll 4
    for (int it = 0; it < 16; it++) {
        int fi4 = (wv * 16 + it) * 64 + lane;
        int c = fi4 >> 5, g = fi4 & 31;
        float4 v = As4[c * 32 + (g ^ (c >> 2))];
        fp += v.x*v.x + v.y*v.y + v.z*v.z + v.w*v.w;
        int e = c - 4 * g;
        if (e >= 0 && e < 4) tp += (&v.x)[e];
    }
#pragma unroll
    for (int o = 1; o < 64; o <<= 1) { fp += __shfl_xor(fp, o, 64); tp += __shfl_xor(tp, o, 64); }
    if (lane == 0) { redS[wv] = fp; redS[4 + wv] = tp; }
    __syncthreads();
    fp = (redS[0] + redS[1]) + (redS[2] + redS[3]);
    tp = (redS[4] + redS[5]) + (redS[6] + redS[7]);
    bool collapsed = (tp * tp < 3.5f * fp);

    if (collapsed) {
#pragma unroll
        for (int rep = 0; rep < 4; rep++) {
            int l4 = rep * 256 + tid;               // 1024 float4 = 32 rows
            int r = rb + (l4 >> 5), g = l4 & 31;
            Bout4[(size_t)r * 32 + g] = As4[r * 32 + (g ^ (r >> 2))];
        }
        return;
    }

    float s2 = 1.0f / fp;       // scale^2 folded into the output write
    int tyy = tid >> 5, txx = tid & 31;
    int r0 = rb + tyy * 4, c0 = txx * 4;
    int rsh = r0 >> 2, csh = c0 >> 2;
    float acc[4][4];
#pragma unroll
    for (int i = 0; i < 4; i++)
#pragma unroll
        for (int j = 0; j < 4; j++) acc[i][j] = 0.f;
#pragma unroll 4
    for (int g = 0; g < 32; g++) {
        float4 a[4], b[4];
        int ga = g ^ rsh, gb = g ^ csh;
#pragma unroll
        for (int i = 0; i < 4; i++) a[i] = As4[(r0 + i) * 32 + ga];
#pragma unroll
        for (int j = 0; j < 4; j++) b[j] = As4[(c0 + j) * 32 + gb];
#pragma unroll
        for (int i = 0; i < 4; i++)
#pragma unroll
            for (int j = 0; j < 4; j++)
                acc[i][j] += a[i].x*b[j].x + a[i].y*b[j].y + a[i].z*b[j].z + a[i].w*b[j].w;
    }
#pragma unroll
    for (int i = 0; i < 4; i++) {
        int row = r0 + i;
        *(float4*)&Bout[row * 128 + c0] =
            make_float4(acc[i][0]*s2, acc[i][1]*s2, acc[i][2]*s2, acc[i][3]*s2);
    }
}

// ---------------- subspace iteration + Rayleigh-Ritz (shuffle Jacobi) ----------------
__global__ __launch_bounds__(256) void k_sub(float* __restrict__ ws, int titer) {
    int band = blockIdx.x, tid = threadIdx.x;
    const float* Ab = ws + A0_OFF + (size_t)band * GSZ;
    __shared__ __align__(16) float VcS[8 * 136];
    __shared__ __align__(16) float WcS[8 * 136];
    __shared__ float LchS[64], invdS[8], B8S[64], E8S[64];
    __shared__ int idx3S[3];

    if (titer == 0) {
        for (int idx = tid; idx < 1024; idx += 256) {
            uint32_t h = (uint32_t)(idx + band * 1024 + 7) * 2654435761u;
            h ^= h >> 15; h *= 0x2c1b3c6du; h ^= h >> 12;
            VcS[(idx >> 7) * 136 + (idx & 127)] = ((float)(h & 0xFFFF) / 32768.0f) - 1.0f;
        }
    } else {
        for (int idx = tid; idx < 1024; idx += 256)
            VcS[(idx >> 7) * 136 + (idx & 127)] = ws[VW_OFF + band * 1024 + idx];
    }
    __syncthreads();

    int c = tid & 127, sq = tid >> 7;           // A*V mapping
    int r8 = tid >> 3, s8 = tid & 7;            // 8x8 mappings (tid<64)
    int steps = (titer == 0) ? 8 : 4;

    for (int step = 0; step <= steps; step++) {
        // ---- W = A * V : thread (c,sq) computes W[c][sq*4 .. sq*4+3].
        {
            const float* V0 = VcS + (sq * 4 + 0) * 136;
            const float* V1 = VcS + (sq * 4 + 1) * 136;
            const float* V2 = VcS + (sq * 4 + 2) * 136;
            const float* V3 = VcS + (sq * 4 + 3) * 136;
            float a0 = 0.f, a1 = 0.f, a2 = 0.f, a3 = 0.f;
#pragma unroll 4
            for (int k = 0; k < 128; k += 4) {
                float g0 = Ab[(k + 0) * 128 + c];
                float g1 = Ab[(k + 1) * 128 + c];
                float g2 = Ab[(k + 2) * 128 + c];
                float g3 = Ab[(k + 3) * 128 + c];
                float4 v0 = *(const float4*)&V0[k];
                float4 v1 = *(const float4*)&V1[k];
                float4 v2 = *(const float4*)&V2[k];
                float4 v3 = *(const float4*)&V3[k];
                a0 += g0 * v0.x + g1 * v0.y + g2 * v0.z + g3 * v0.w;
                a1 += g0 * v1.x + g1 * v1.y + g2 * v1.z + g3 * v1.w;
                a2 += g0 * v2.x + g1 * v2.y + g2 * v2.z + g3 * v2.w;
                a3 += g0 * v3.x + g1 * v3.y + g2 * v3.z + g3 * v3.w;
            }
            WcS[(sq * 4 + 0) * 136 + c] = a0;
            WcS[(sq * 4 + 1) * 136 + c] = a1;
            WcS[(sq * 4 + 2) * 136 + c] = a2;
            WcS[(sq * 4 + 3) * 136 + c] = a3;
        }
        __syncthreads();
        if (step == steps) break;

        // ---- CholQR: M = W^T W (wave 0), Cholesky in registers via shuffles
        if (tid < 64) {
            const float* wr = WcS + r8 * 136;
            const float* wc = WcS + s8 * 136;
            float m = 0.f;
#pragma unroll 8
            for (int k = 0; k < 128; k += 4) {
                float4 p = *(const float4*)&wr[k];
                float4 q = *(const float4*)&wc[k];
                m += p.x * q.x + p.y * q.y + p.z * q.z + p.w * q.w;
            }
            float t = (r8 == s8) ? m : 0.f;
#pragma unroll
            for (int o = 1; o < 64; o <<= 1) t += __shfl_xor(t, o, 64);
            float eps = 1e-12f * t + 1e-35f;
            float v = m;
#pragma unroll
            for (int j = 0; j < 8; j++) {
                float dj = __shfl(v, j * 9, 64);
                dj = fmaxf(dj, eps);
                float lj = sqrtf(dj);
                float inv = 1.f / lj;
                if (s8 == j) v = (r8 == j) ? lj : (r8 > j ? v * inv : v);
                float Lr = __shfl(v, r8 * 8 + j, 64);
                float Ls = __shfl(v, s8 * 8 + j, 64);
                if (r8 > j && s8 > j) v -= Lr * Ls;
                if (tid == j) invdS[j] = inv;
            }
            LchS[tid] = v;
        }
        __syncthreads();
        // ---- backsolve V = W L^-T (rows in parallel, tid<128)
        if (tid < 128) {
            float w[8], vv[8];
#pragma unroll
            for (int s = 0; s < 8; s++) w[s] = WcS[s * 136 + tid];
#pragma unroll
            for (int s = 0; s < 8; s++) {
                float t2 = w[s];
                for (int j = 0; j < s; j++) t2 -= vv[j] * LchS[s * 8 + j];
                vv[s] = t2 * invdS[s];
                VcS[s * 136 + tid] = vv[s];
            }
        }
        __syncthreads();
    }

    // ---- Rayleigh-Ritz + symmetrize + Jacobi, all in wave-0 registers
    if (tid < 64) {
        const float* vr = VcS + r8 * 136;
        const float* wc = WcS + s8 * 136;
        float m = 0.f;
#pragma unroll 8
        for (int k = 0; k < 128; k += 4) {
            float4 p = *(const float4*)&vr[k];
            float4 q = *(const float4*)&wc[k];
            m += p.x * q.x + p.y * q.y + p.z * q.z + p.w * q.w;
        }
        float mT = __shfl(m, s8 * 8 + r8, 64);      // symmetrize via shuffle
        float b = 0.5f * (m + mT);
        float e = (r8 == s8) ? 1.f : 0.f;

        for (int sweep = 0; sweep < 6; sweep++) {
            for (int rd = 0; rd < 7; rd++) {
                int pr = (r8 == 7) ? rd : ((r8 == rd) ? 7 : (2 * rd + 7 - r8) % 7);
                int pc = (s8 == 7) ? rd : ((s8 == rd) ? 7 : (2 * rd + 7 - s8) % 7);
                int P = min(r8, pr), Q = max(r8, pr);
                int Pc = min(s8, pc), Qc = max(s8, pc);
                float app = __shfl(b, P * 9, 64);
                float aqq = __shfl(b, Q * 9, 64);
                float apq = __shfl(b, P * 8 + Q, 64);
                float cR, sR;
                if (fabsf(apq) < 1e-28f) { cR = 1.f; sR = 0.f; }
                else {
                    float tau = (aqq - app) / (2.f * apq);
                    float tt = ((tau >= 0.f) ? 1.f : -1.f) / (fabsf(tau) + sqrtf(1.f + tau * tau));
                    cR = rsqrtf(1.f + tt * tt); sR = tt * cR;
                }
                float ap2 = __shfl(b, Pc * 9, 64);
                float aq2 = __shfl(b, Qc * 9, 64);
                float apq2 = __shfl(b, Pc * 8 + Qc, 64);
                float cC, sC;
                if (fabsf(apq2) < 1e-28f) { cC = 1.f; sC = 0.f; }
                else {
                    float tau = (aq2 - ap2) / (2.f * apq2);
                    float tt = ((tau >= 0.f) ? 1.f : -1.f) / (fabsf(tau) + sqrtf(1.f + tau * tau));
                    cC = rsqrtf(1.f + tt * tt); sC = tt * cC;
                }
                // row update: B <- J^T B
                float tv = __shfl(b, pr * 8 + s8, 64);
                float bn = (r8 < pr) ? (cR * b - sR * tv) : (sR * tv + cR * b);
                // col update on row-updated B: B <- B J
                float t2 = __shfl(bn, r8 * 8 + pc, 64);
                b = (s8 < pc) ? (cC * bn - sC * t2) : (sC * t2 + cC * bn);
                // E <- E J
                float e2 = __shfl(e, r8 * 8 + pc, 64);
                e = (s8 < pc) ? (cC * e - sC * e2) : (sC * e2 + cC * e);
            }
        }
        B8S[tid] = b;
        E8S[tid] = e;
        if (tid == 0) {
            int used = 0;
            for (int r = 0; r < 3; r++) {
                int best = 0; float bv = -1e38f;
                for (int s = 0; s < 8; s++)
                    if (!(used & (1 << s)) && B8S[s * 9] > bv) { bv = B8S[s * 9]; best = s; }
                used |= 1 << best;
                idx3S[r] = best;
            }
        }
    }
    __syncthreads();

    // ---- U = V * E[:, idx3], warm-start save
    if (tid < 128) {
        float e[3][8];
#pragma unroll
        for (int r = 0; r < 3; r++)
#pragma unroll
            for (int s = 0; s < 8; s++) e[r][s] = E8S[s * 8 + idx3S[r]];
        float vcl[8];
#pragma unroll
        for (int s = 0; s < 8; s++) vcl[s] = VcS[s * 136 + tid];
#pragma unroll
        for (int r = 0; r < 3; r++) {
            float u = 0.f;
#pragma unroll
            for (int s = 0; s < 8; s++) u += vcl[s] * e[r][s];
            ws[U3_OFF + band * 384 + tid * 3 + r] = u;
        }
#pragma unroll
        for (int s = 0; s < 8; s++) ws[VW_OFF + band * 1024 + s * 128 + tid] = vcl[s];
    }
}

// ---------------- fused: utl = U^T L (phase 1, LDS) + UV/losses/L_new (phase 2) ----------------
__global__ __launch_bounds__(256) void k_upd(const float* __restrict__ x,
                                             const float* __restrict__ W,
                                             const float* __restrict__ xg,
                                             float* __restrict__ out,
                                             float* __restrict__ ws,
                                             float alphapow, int writeUV, int titer) {
    int band = blockIdx.y, xc = blockIdx.x, tid = threadIdx.x;
    int w = tid >> 6, lane = tid & 63;
    int n0 = xc * 256, p4 = lane * 4;
    __shared__ float Us[128][4];
    __shared__ __align__(16) float up[12][260];   // per-wave utl partials [w*3+r][px]
    __shared__ __align__(16) float um[3][260];    // reduced utl
    __shared__ float red[16];

    if (tid < 128) {
        Us[tid][0] = ws[U3_OFF + band * 384 + tid * 3 + 0];
        Us[tid][1] = ws[U3_OFF + band * 384 + tid * 3 + 1];
        Us[tid][2] = ws[U3_OFF + band * 384 + tid * 3 + 2];
    }
    __syncthreads();

    // ---- phase 1: utl[r][p] = sum_c U[c][r] * L[c][p]
    const float* Lb = ws + L_OFF + (size_t)band * CHN * NPIX;
    float4 a0 = make_float4(0.f,0.f,0.f,0.f), a1 = a0, a2 = a0;
    for (int cg = 0; cg < 32; cg++) {
        int c = cg * 4 + w;
        float4 lv = *(const float4*)(Lb + (size_t)c * NPIX + n0 + p4);
        float u0 = Us[c][0], u1 = Us[c][1], u2 = Us[c][2];
        a0.x += u0 * lv.x; a0.y += u0 * lv.y; a0.z += u0 * lv.z; a0.w += u0 * lv.w;
        a1.x += u1 * lv.x; a1.y += u1 * lv.y; a1.z += u1 * lv.z; a1.w += u1 * lv.w;
        a2.x += u2 * lv.x; a2.y += u2 * lv.y; a2.z += u2 * lv.z; a2.w += u2 * lv.w;
    }
    *(float4*)&up[w * 3 + 0][p4] = a0;
    *(float4*)&up[w * 3 + 1][p4] = a1;
    *(float4*)&up[w * 3 + 2][p4] = a2;
    __syncthreads();
    if (tid < 192) {
        int r = tid >> 6, l = (tid & 63) * 4;
        float4 s0 = *(float4*)&up[r][l];
        float4 s1 = *(float4*)&up[3 + r][l];
        float4 s2 = *(float4*)&up[6 + r][l];
        float4 s3 = *(float4*)&up[9 + r][l];
        *(float4*)&um[r][l] = make_float4(s0.x + s1.x + s2.x + s3.x,
                                          s0.y + s1.y + s2.y + s3.y,
                                          s0.z + s1.z + s2.z + s3.z,
                                          s0.w + s1.w + s2.w + s3.w);
    }
    __syncthreads();

    // ---- phase 2: stream x/W/xg, compute UV, losses, L_new (and out at t=9)
    double sw = *(const double*)ws;
    float rho = 0.5f * (float)(sw / (double)NTOT) * alphapow;
    float4 t0 = *(float4*)&um[0][p4];
    float4 t1 = *(float4*)&um[1][p4];
    float4 t2 = *(float4*)&um[2][p4];
    float lf = 0.f, ll = 0.f;
    size_t base = (size_t)band * CHN * NPIX + n0 + p4;
    float* Lp = ws + L_OFF;
#pragma unroll 2
    for (int cg = 0; cg < 32; cg++) {
        int c = cg * 4 + w;
        size_t idx = base + (size_t)c * NPIX;
        float4 xv = *(const float4*)(x + idx);
        float4 wv = *(const float4*)(W + idx);
        float4 gv = *(const float4*)(xg + idx);
        float u0 = Us[c][0], u1 = Us[c][1], u2 = Us[c][2];
        float4 uv, ln;
        uv.x = u0 * t0.x + u1 * t1.x + u2 * t2.x;
        uv.y = u0 * t0.y + u1 * t1.y + u2 * t2.y;
        uv.z = u0 * t0.z + u1 * t1.z + u2 * t2.z;
        uv.w = u0 * t0.w + u1 * t1.w + u2 * t2.w;
        float dx0 = uv.x - xv.x, dx1 = uv.y - xv.y, dx2 = uv.z - xv.z, dx3 = uv.w - xv.w;
        lf += wv.x * dx0 * dx0 + wv.y * dx1 * dx1 + wv.z * dx2 * dx2 + wv.w * dx3 * dx3;
        float g0 = uv.x - gv.x, g1 = uv.y - gv.y, g2 = uv.z - gv.z, g3 = uv.w - gv.w;
        ll += g0 * g0 + g1 * g1 + g2 * g2 + g3 * g3;
        ln.x = xv.x + (rho / (wv.x + rho)) * dx0;
        ln.y = xv.y + (rho / (wv.y + rho)) * dx1;
        ln.z = xv.z + (rho / (wv.z + rho)) * dx2;
        ln.w = xv.w + (rho / (wv.w + rho)) * dx3;
        *(float4*)(Lp + idx) = ln;
        if (writeUV) *(float4*)(out + idx) = uv;
    }
    for (int o = 32; o > 0; o >>= 1) { lf += __shfl_down(lf, o, 64); ll += __shfl_down(ll, o, 64); }
    if (lane == 0) { red[w] = lf; red[8 + w] = ll; }
    __syncthreads();
    if (tid == 0) {
        float a = red[0] + red[1] + red[2] + red[3];
        float b = red[8] + red[9] + red[10] + red[11];
        atomicAdd((double*)ws + 1 + titer,  (double)a);
        atomicAdd((double*)ws + 11 + titer, (double)b);
    }
}

// ---------------- finalize losses ----------------
__global__ void k_final(float* __restrict__ out, const float* __restrict__ ws) {
    int tid = threadIdx.x;
    const double* d = (const double*)ws;
    if (tid < 10)       out[NTOT + tid] = (float)(d[1 + tid] / (double)NTOT);
    else if (tid < 20)  out[NTOT + tid] = (float)(d[11 + (tid - 10)] / (double)NTOT);
}

extern "C" void kernel_launch(void* const* d_in, const int* in_sizes, int n_in,
                              void* d_out, int out_size, void* d_ws, size_t ws_size,
                              hipStream_t stream) {
    const float* x  = (const float*)d_in[0];
    const float* W  = (const float*)d_in[1];
    const float* xg = (const float*)d_in[2];
    float* out = (float*)d_out;
    float* ws = (float*)d_ws;

    hipMemsetAsync(d_ws, 0, 4096, stream);   // zero scalar/accumulator block
    k_init<<<2048, 256, 0, stream>>>(x, W, ws);

    float ap = 1.0f;
    for (int t = 0; t < 10; t++) {
        k_gram<<<dim3(8, 32), 256, 0, stream>>>(ws);
        for (int j = 0; j < KSQ; j++) {
            // stage0: GP(sum of 8) -> A1; then A1->A0->...->A0 (final in A0)
            int inOff  = (j & 1) ? A1_OFF : A0_OFF;   // ignored when j==0
            int outOff = (j & 1) ? A0_OFF : A1_OFF;
            k_sq<<<dim3(4, 32), 256, 0, stream>>>(ws, inOff, outOff, (j == 0) ? 1 : 0);
        }
        k_sub<<<32, 256, 0, stream>>>(ws, t);
        k_upd<<<dim3(16, 32), 256, 0, stream>>>(x, W, xg, out, ws, ap, (t == 9) ? 1 : 0, t);
        ap *= 1.05f;
    }
    k_final<<<1, 64, 0, stream>>>(out, ws);
}

// Round 3
// 1901.502 us; speedup vs baseline: 2.0423x; 1.4299x over previous
//
#include <hip/hip_runtime.h>
#include <stdint.h>

#define BANDS 32
#define CHN   128
#define NPIX  4096
#define NTOT  16777216          // 32*128*4096
#define GSZ   16384             // 128*128
#define KSQ   6                 // squaring stages (G -> G^64, collapse-guarded)

// ---------------- ws layout (float indices) ----------------
// bytes [0..168): doubles: [0]=sumW, [1..10]=lossF acc, [11..20]=loss acc
#define L_OFF    1024
#define GP_OFF   (L_OFF + NTOT)                  // 32*8*16384 gram partials
#define A0_OFF   (GP_OFF + BANDS*8*GSZ)          // (unused now, kept for layout)
#define A1_OFF   (A0_OFF + BANDS*GSZ)
#define U3_OFF   (A1_OFF + BANDS*GSZ)            // 32*128*3
#define VW_OFF   (U3_OFF + BANDS*CHN*3)          // 32*128*8 warm-start basis

typedef short s16x8 __attribute__((ext_vector_type(8)));
typedef float f32x4 __attribute__((ext_vector_type(4)));

__device__ __forceinline__ unsigned short bf16rn(float x) {
    uint32_t u = __float_as_uint(x);
    u += 0x7FFFu + ((u >> 16) & 1u);
    return (unsigned short)(u >> 16);
}
__device__ __forceinline__ float bf16tof(unsigned short h) {
    return __uint_as_float((uint32_t)h << 16);
}

// ---------------- init: L = x, sumW reduction ----------------
__global__ __launch_bounds__(256) void k_init(const float* __restrict__ x,
                                              const float* __restrict__ W,
                                              float* __restrict__ ws) {
    int gid = blockIdx.x * 256 + threadIdx.x;       // 2048*256 threads
    const float4* x4 = (const float4*)x;
    const float4* w4 = (const float4*)W;
    float4* L4 = (float4*)(ws + L_OFF);
    float s = 0.f;
#pragma unroll
    for (int i = 0; i < 8; i++) {
        int idx = gid + i * 524288;                 // NTOT/4 = 4194304
        float4 xv = x4[idx];
        float4 wv = w4[idx];
        L4[idx] = xv;
        s += wv.x + wv.y + wv.z + wv.w;
    }
    for (int o = 32; o > 0; o >>= 1) s += __shfl_down(s, o, 64);
    __shared__ float red[4];
    int wid = threadIdx.x >> 6, lane = threadIdx.x & 63;
    if (lane == 0) red[wid] = s;
    __syncthreads();
    if (threadIdx.x == 0) {
        float t = red[0] + red[1] + red[2] + red[3];
        atomicAdd((double*)ws, (double)t);
    }
}

// ---------------- gram: partial G[b] = L L^T via bf16x2-split MFMA ----------------
// (verified round 2: fragment pattern + C-layout correct on HW)
__global__ __launch_bounds__(256) void k_gram(float* __restrict__ ws) {
    int band = blockIdx.y, kc = blockIdx.x, tid = threadIdx.x;
    __shared__ __align__(16) unsigned short Hs[8192];   // 128x64 bf16 hi, XOR-swizzled
    __shared__ __align__(16) unsigned short Lo[8192];   // lo part
    const float* Lb = ws + L_OFF + (size_t)band * CHN * NPIX;
    int k0 = kc * 512;
    int lane = tid & 63, wv = tid >> 6;
    int wr = (wv >> 1) * 64, wcb = (wv & 1) * 64;
    int l15 = lane & 15, l4g = lane >> 4;

    f32x4 acc[4][4];
#pragma unroll
    for (int m = 0; m < 4; m++)
#pragma unroll
        for (int n = 0; n < 4; n++) acc[m][n] = (f32x4){0.f, 0.f, 0.f, 0.f};

    int srow = tid >> 3, scol = (tid & 7) * 8;          // staging map: 32 rows/pass, 8px chunks

    float4 pre[8];                                       // register prefetch (T14)
#pragma unroll
    for (int p = 0; p < 4; p++) {
        const float* src = Lb + (size_t)(srow + p * 32) * NPIX + k0 + scol;
        pre[2 * p]     = *(const float4*)src;
        pre[2 * p + 1] = *(const float4*)(src + 4);
    }
#pragma unroll 1
    for (int t = 0; t < 8; t++) {                        // 8 K-tiles of 64 px
#pragma unroll
        for (int p = 0; p < 4; p++) {
            int row = srow + p * 32;
            float vv[8] = {pre[2*p].x, pre[2*p].y, pre[2*p].z, pre[2*p].w,
                           pre[2*p+1].x, pre[2*p+1].y, pre[2*p+1].z, pre[2*p+1].w};
            s16x8 hv, lv;
#pragma unroll
            for (int e = 0; e < 8; e++) {
                unsigned short h = bf16rn(vv[e]);
                float r = vv[e] - bf16tof(h);
                hv[e] = (short)h;
                lv[e] = (short)bf16rn(r);
            }
            int off = row * 128 + ((scol * 2) ^ ((row & 7) << 4));
            *(s16x8*)((char*)Hs + off) = hv;
            *(s16x8*)((char*)Lo + off) = lv;
        }
        __syncthreads();
        if (t < 7) {
            int kn = k0 + (t + 1) * 64;
#pragma unroll
            for (int p = 0; p < 4; p++) {
                const float* src = Lb + (size_t)(srow + p * 32) * NPIX + kn + scol;
                pre[2 * p]     = *(const float4*)src;
                pre[2 * p + 1] = *(const float4*)(src + 4);
            }
        }
#pragma unroll
        for (int ks = 0; ks < 2; ks++) {
            int kb2 = ks * 64 + l4g * 16;
            s16x8 Ah[4], Al[4], Bh[4], Bl[4];
#pragma unroll
            for (int m = 0; m < 4; m++) {
                int row = wr + m * 16 + l15;
                int off = row * 128 + (kb2 ^ ((row & 7) << 4));
                Ah[m] = *(const s16x8*)((const char*)Hs + off);
                Al[m] = *(const s16x8*)((const char*)Lo + off);
            }
#pragma unroll
            for (int n = 0; n < 4; n++) {
                int row = wcb + n * 16 + l15;
                int off = row * 128 + (kb2 ^ ((row & 7) << 4));
                Bh[n] = *(const s16x8*)((const char*)Hs + off);
                Bl[n] = *(const s16x8*)((const char*)Lo + off);
            }
#pragma unroll
            for (int m = 0; m < 4; m++)
#pragma unroll
                for (int n = 0; n < 4; n++) {
                    acc[m][n] = __builtin_amdgcn_mfma_f32_16x16x32_bf16(Ah[m], Bh[n], acc[m][n], 0, 0, 0);
                    acc[m][n] = __builtin_amdgcn_mfma_f32_16x16x32_bf16(Ah[m], Bl[n], acc[m][n], 0, 0, 0);
                    acc[m][n] = __builtin_amdgcn_mfma_f32_16x16x32_bf16(Al[m], Bh[n], acc[m][n], 0, 0, 0);
                }
        }
        __syncthreads();
    }
    float* Gp = ws + GP_OFF + (size_t)(band * 8 + kc) * GSZ;
#pragma unroll
    for (int m = 0; m < 4; m++)
#pragma unroll
        for (int n = 0; n < 4; n++) {
            int row0 = wr + m * 16 + l4g * 4;
            int col  = wcb + n * 16 + l15;
#pragma unroll
            for (int r = 0; r < 4; r++)
                Gp[(row0 + r) * 128 + col] = acc[m][n][r];
        }
}

// ---------------- k_eig: fused {sum partials, 6x collapse-guarded squaring (MFMA),
//                  subspace iteration, CholQR, Rayleigh-Ritz, Jacobi} per band ----------------
// One block per band; A lives in LDS throughout. Squaring = bf16x2-split 3-MFMA on the
// (bitwise-symmetric) A, rows x rows — same verified pattern as k_gram. Collapse guard:
// once tr^2 < 3.5*fro^2 the old code copied A unchanged forever after (stats invariant),
// so `break` is exactly equivalent.
__global__ __launch_bounds__(256) void k_eig(float* __restrict__ ws, int titer) {
    int band = blockIdx.x, tid = threadIdx.x;
    __shared__ __align__(16) float Aa[128 * 132];            // fp32 A, stride 132
    __shared__ __align__(16) unsigned short HiS[128 * 128];  // bf16 hi, XOR-swizzled 256B rows
    __shared__ __align__(16) unsigned short LoS[128 * 128];  // bf16 lo
    __shared__ __align__(16) float VcS[8 * 136];
    __shared__ __align__(16) float WcS[8 * 136];
    __shared__ float LchS[64], invdS[8], B8S[64], E8S[64], redS[8];
    __shared__ int idx3S[3];

    int lane = tid & 63, wv = tid >> 6;
    int l15 = lane & 15, l4g = lane >> 4;
    int wr = (wv >> 1) * 64, wcb = (wv & 1) * 64;

    // ---- load G = sum of 8 gram partials -> Aa, with stats
    const float4* Gp4 = (const float4*)(ws + GP_OFF + (size_t)band * 8 * GSZ);
    float fp = 0.f, tp = 0.f;
#pragma unroll
    for (int rep = 0; rep < 16; rep++) {
        int fi4 = rep * 256 + tid;
        float4 v = Gp4[fi4];
#pragma unroll
        for (int p = 1; p < 8; p++) {
            float4 u = Gp4[p * 4096 + fi4];
            v.x += u.x; v.y += u.y; v.z += u.z; v.w += u.w;
        }
        int r = fi4 >> 5, c4 = (fi4 & 31) * 4;
        *(float4*)&Aa[r * 132 + c4] = v;
        fp += v.x*v.x + v.y*v.y + v.z*v.z + v.w*v.w;
        int e = r - c4;
        if (e >= 0 && e < 4) tp += (&v.x)[e];
    }
#pragma unroll
    for (int o = 1; o < 64; o <<= 1) { fp += __shfl_xor(fp, o, 64); tp += __shfl_xor(tp, o, 64); }
    if (lane == 0) { redS[wv] = fp; redS[4 + wv] = tp; }
    __syncthreads();
    fp = (redS[0] + redS[1]) + (redS[2] + redS[3]);
    tp = (redS[4] + redS[5]) + (redS[6] + redS[7]);

    // ---- squaring chain, in place
    for (int j = 0; j < KSQ; j++) {
        if (tp * tp < 3.5f * fp) break;          // uniform across block
        float s2 = 1.0f / fp;
        // convert Aa -> Hi/Lo (each thread 64 elems = 8 groups of 8)
#pragma unroll
        for (int rep = 0; rep < 8; rep++) {
            int idx8 = rep * 256 + tid;          // 0..2047
            int row = idx8 >> 4, c8 = (idx8 & 15) * 8;
            float4 v0 = *(const float4*)&Aa[row * 132 + c8];
            float4 v1 = *(const float4*)&Aa[row * 132 + c8 + 4];
            float vv[8] = {v0.x, v0.y, v0.z, v0.w, v1.x, v1.y, v1.z, v1.w};
            s16x8 hv, lv;
#pragma unroll
            for (int e = 0; e < 8; e++) {
                unsigned short h = bf16rn(vv[e]);
                float r = vv[e] - bf16tof(h);
                hv[e] = (short)h;
                lv[e] = (short)bf16rn(r);
            }
            int off = row * 256 + ((c8 * 2) ^ ((row & 7) << 4));
            *(s16x8*)((char*)HiS + off) = hv;
            *(s16x8*)((char*)LoS + off) = lv;
        }
        __syncthreads();
        // MFMA: wave quadrant (wr, wcb), 4x4 tiles of 16x16, K=128 in 4 steps
        f32x4 acc[4][4];
#pragma unroll
        for (int m = 0; m < 4; m++)
#pragma unroll
            for (int n = 0; n < 4; n++) acc[m][n] = (f32x4){0.f, 0.f, 0.f, 0.f};
#pragma unroll
        for (int ks = 0; ks < 4; ks++) {
            int kb = ks * 64 + l4g * 16;
            s16x8 Ah[4], Al[4], Bh[4], Bl[4];
#pragma unroll
            for (int m = 0; m < 4; m++) {
                int row = wr + m * 16 + l15;
                int off = row * 256 + (kb ^ ((row & 7) << 4));
                Ah[m] = *(const s16x8*)((const char*)HiS + off);
                Al[m] = *(const s16x8*)((const char*)LoS + off);
            }
#pragma unroll
            for (int n = 0; n < 4; n++) {
                int row = wcb + n * 16 + l15;
                int off = row * 256 + (kb ^ ((row & 7) << 4));
                Bh[n] = *(const s16x8*)((const char*)HiS + off);
                Bl[n] = *(const s16x8*)((const char*)LoS + off);
            }
#pragma unroll
            for (int m = 0; m < 4; m++)
#pragma unroll
                for (int n = 0; n < 4; n++) {
                    acc[m][n] = __builtin_amdgcn_mfma_f32_16x16x32_bf16(Ah[m], Bh[n], acc[m][n], 0, 0, 0);
                    acc[m][n] = __builtin_amdgcn_mfma_f32_16x16x32_bf16(Ah[m], Bl[n], acc[m][n], 0, 0, 0);
                    acc[m][n] = __builtin_amdgcn_mfma_f32_16x16x32_bf16(Al[m], Bh[n], acc[m][n], 0, 0, 0);
                }
        }
        // writeback (scaled) + next-stage stats from accumulators
        float nfp = 0.f, ntp = 0.f;
#pragma unroll
        for (int m = 0; m < 4; m++)
#pragma unroll
            for (int n = 0; n < 4; n++)
#pragma unroll
                for (int r = 0; r < 4; r++) {
                    int row = wr + m * 16 + l4g * 4 + r;
                    int col = wcb + n * 16 + l15;
                    float val = s2 * acc[m][n][r];
                    Aa[row * 132 + col] = val;
                    nfp += val * val;
                    if (row == col) ntp += val;
                }
#pragma unroll
        for (int o = 1; o < 64; o <<= 1) { nfp += __shfl_xor(nfp, o, 64); ntp += __shfl_xor(ntp, o, 64); }
        if (lane == 0) { redS[wv] = nfp; redS[4 + wv] = ntp; }
        __syncthreads();
        fp = (redS[0] + redS[1]) + (redS[2] + redS[3]);
        tp = (redS[4] + redS[5]) + (redS[6] + redS[7]);
    }

    // ---- subspace iteration on Aa (LDS) ----
    if (titer == 0) {
        for (int idx = tid; idx < 1024; idx += 256) {
            uint32_t h = (uint32_t)(idx + band * 1024 + 7) * 2654435761u;
            h ^= h >> 15; h *= 0x2c1b3c6du; h ^= h >> 12;
            VcS[(idx >> 7) * 136 + (idx & 127)] = ((float)(h & 0xFFFF) / 32768.0f) - 1.0f;
        }
    } else {
        for (int idx = tid; idx < 1024; idx += 256)
            VcS[(idx >> 7) * 136 + (idx & 127)] = ws[VW_OFF + band * 1024 + idx];
    }
    __syncthreads();

    int c = tid & 127, sq = tid >> 7;           // A*V mapping
    int r8 = tid >> 3, s8 = tid & 7;            // 8x8 mappings (tid<64)
    int steps = (titer == 0) ? 8 : 4;

    for (int step = 0; step <= steps; step++) {
        {
            const float* V0 = VcS + (sq * 4 + 0) * 136;
            const float* V1 = VcS + (sq * 4 + 1) * 136;
            const float* V2 = VcS + (sq * 4 + 2) * 136;
            const float* V3 = VcS + (sq * 4 + 3) * 136;
            float a0 = 0.f, a1 = 0.f, a2 = 0.f, a3 = 0.f;
#pragma unroll 4
            for (int k = 0; k < 128; k += 4) {
                float g0 = Aa[(k + 0) * 132 + c];
                float g1 = Aa[(k + 1) * 132 + c];
                float g2 = Aa[(k + 2) * 132 + c];
                float g3 = Aa[(k + 3) * 132 + c];
                float4 v0 = *(const float4*)&V0[k];
                float4 v1 = *(const float4*)&V1[k];
                float4 v2 = *(const float4*)&V2[k];
                float4 v3 = *(const float4*)&V3[k];
                a0 += g0 * v0.x + g1 * v0.y + g2 * v0.z + g3 * v0.w;
                a1 += g0 * v1.x + g1 * v1.y + g2 * v1.z + g3 * v1.w;
                a2 += g0 * v2.x + g1 * v2.y + g2 * v2.z + g3 * v2.w;
                a3 += g0 * v3.x + g1 * v3.y + g2 * v3.z + g3 * v3.w;
            }
            WcS[(sq * 4 + 0) * 136 + c] = a0;
            WcS[(sq * 4 + 1) * 136 + c] = a1;
            WcS[(sq * 4 + 2) * 136 + c] = a2;
            WcS[(sq * 4 + 3) * 136 + c] = a3;
        }
        __syncthreads();
        if (step == steps) break;

        if (tid < 64) {
            const float* wrp = WcS + r8 * 136;
            const float* wcp = WcS + s8 * 136;
            float m = 0.f;
#pragma unroll 8
            for (int k = 0; k < 128; k += 4) {
                float4 p = *(const float4*)&wrp[k];
                float4 q = *(const float4*)&wcp[k];
                m += p.x * q.x + p.y * q.y + p.z * q.z + p.w * q.w;
            }
            float t = (r8 == s8) ? m : 0.f;
#pragma unroll
            for (int o = 1; o < 64; o <<= 1) t += __shfl_xor(t, o, 64);
            float eps = 1e-12f * t + 1e-35f;
            float v = m;
#pragma unroll
            for (int j = 0; j < 8; j++) {
                float dj = __shfl(v, j * 9, 64);
                dj = fmaxf(dj, eps);
                float lj = sqrtf(dj);
                float inv = 1.f / lj;
                if (s8 == j) v = (r8 == j) ? lj : (r8 > j ? v * inv : v);
                float Lr = __shfl(v, r8 * 8 + j, 64);
                float Ls = __shfl(v, s8 * 8 + j, 64);
                if (r8 > j && s8 > j) v -= Lr * Ls;
                if (tid == j) invdS[j] = inv;
            }
            LchS[tid] = v;
        }
        __syncthreads();
        if (tid < 128) {
            float w[8], vv[8];
#pragma unroll
            for (int s = 0; s < 8; s++) w[s] = WcS[s * 136 + tid];
#pragma unroll
            for (int s = 0; s < 8; s++) {
                float t2 = w[s];
                for (int j = 0; j < s; j++) t2 -= vv[j] * LchS[s * 8 + j];
                vv[s] = t2 * invdS[s];
                VcS[s * 136 + tid] = vv[s];
            }
        }
        __syncthreads();
    }

    // ---- Rayleigh-Ritz + Jacobi (wave-0 registers)
    if (tid < 64) {
        const float* vr = VcS + r8 * 136;
        const float* wcp = WcS + s8 * 136;
        float m = 0.f;
#pragma unroll 8
        for (int k = 0; k < 128; k += 4) {
            float4 p = *(const float4*)&vr[k];
            float4 q = *(const float4*)&wcp[k];
            m += p.x * q.x + p.y * q.y + p.z * q.z + p.w * q.w;
        }
        float mT = __shfl(m, s8 * 8 + r8, 64);
        float b = 0.5f * (m + mT);
        float e = (r8 == s8) ? 1.f : 0.f;

        for (int sweep = 0; sweep < 6; sweep++) {
            for (int rd = 0; rd < 7; rd++) {
                int pr = (r8 == 7) ? rd : ((r8 == rd) ? 7 : (2 * rd + 7 - r8) % 7);
                int pc = (s8 == 7) ? rd : ((s8 == rd) ? 7 : (2 * rd + 7 - s8) % 7);
                int P = min(r8, pr), Q = max(r8, pr);
                int Pc = min(s8, pc), Qc = max(s8, pc);
                float app = __shfl(b, P * 9, 64);
                float aqq = __shfl(b, Q * 9, 64);
                float apq = __shfl(b, P * 8 + Q, 64);
                float cR, sR;
                if (fabsf(apq) < 1e-28f) { cR = 1.f; sR = 0.f; }
                else {
                    float tau = (aqq - app) / (2.f * apq);
                    float tt = ((tau >= 0.f) ? 1.f : -1.f) / (fabsf(tau) + sqrtf(1.f + tau * tau));
                    cR = rsqrtf(1.f + tt * tt); sR = tt * cR;
                }
                float ap2 = __shfl(b, Pc * 9, 64);
                float aq2 = __shfl(b, Qc * 9, 64);
                float apq2 = __shfl(b, Pc * 8 + Qc, 64);
                float cC, sC;
                if (fabsf(apq2) < 1e-28f) { cC = 1.f; sC = 0.f; }
                else {
                    float tau = (aq2 - ap2) / (2.f * apq2);
                    float tt = ((tau >= 0.f) ? 1.f : -1.f) / (fabsf(tau) + sqrtf(1.f + tau * tau));
                    cC = rsqrtf(1.f + tt * tt); sC = tt * cC;
                }
                float tv = __shfl(b, pr * 8 + s8, 64);
                float bn = (r8 < pr) ? (cR * b - sR * tv) : (sR * tv + cR * b);
                float t2 = __shfl(bn, r8 * 8 + pc, 64);
                b = (s8 < pc) ? (cC * bn - sC * t2) : (sC * t2 + cC * bn);
                float e2 = __shfl(e, r8 * 8 + pc, 64);
                e = (s8 < pc) ? (cC * e - sC * e2) : (sC * e2 + cC * e);
            }
        }
        B8S[tid] = b;
        E8S[tid] = e;
        if (tid == 0) {
            int used = 0;
            for (int r = 0; r < 3; r++) {
                int best = 0; float bv = -1e38f;
                for (int s = 0; s < 8; s++)
                    if (!(used & (1 << s)) && B8S[s * 9] > bv) { bv = B8S[s * 9]; best = s; }
                used |= 1 << best;
                idx3S[r] = best;
            }
        }
    }
    __syncthreads();

    // ---- U = V * E[:, idx3], warm-start save
    if (tid < 128) {
        float e[3][8];
#pragma unroll
        for (int r = 0; r < 3; r++)
#pragma unroll
            for (int s = 0; s < 8; s++) e[r][s] = E8S[s * 8 + idx3S[r]];
        float vcl[8];
#pragma unroll
        for (int s = 0; s < 8; s++) vcl[s] = VcS[s * 136 + tid];
#pragma unroll
        for (int r = 0; r < 3; r++) {
            float u = 0.f;
#pragma unroll
            for (int s = 0; s < 8; s++) u += vcl[s] * e[r][s];
            ws[U3_OFF + band * 384 + tid * 3 + r] = u;
        }
#pragma unroll
        for (int s = 0; s < 8; s++) ws[VW_OFF + band * 1024 + s * 128 + tid] = vcl[s];
    }
}

// ---------------- fused: utl = U^T L (phase 1) + UV/losses/L_new (phase 2) ----------------
// 1024 blocks (128-px chunks) for 4 blocks/CU. Thread: wave w, half = lane>>5,
// cs = w*2+half in 0..7 (channel subgroup), l32 covers 128 px as float4.
__global__ __launch_bounds__(256) void k_upd(const float* __restrict__ x,
                                             const float* __restrict__ W,
                                             const float* __restrict__ xg,
                                             float* __restrict__ out,
                                             float* __restrict__ ws,
                                             float alphapow, int writeUV, int titer) {
    int band = blockIdx.y, xc = blockIdx.x, tid = threadIdx.x;
    int w = tid >> 6, lane = tid & 63;
    int half = lane >> 5, l32 = lane & 31;
    int n0 = xc * 128, p4 = l32 * 4;
    int cs = w * 2 + half;                       // 0..7
    __shared__ float Us[128][4];
    __shared__ __align__(16) float up[24][132];  // partials [cs*3+r][px]
    __shared__ __align__(16) float um[3][132];   // reduced utl
    __shared__ float red[16];

    if (tid < 128) {
        Us[tid][0] = ws[U3_OFF + band * 384 + tid * 3 + 0];
        Us[tid][1] = ws[U3_OFF + band * 384 + tid * 3 + 1];
        Us[tid][2] = ws[U3_OFF + band * 384 + tid * 3 + 2];
    }
    __syncthreads();

    // ---- phase 1: utl[r][p] = sum_c U[c][r] * L[c][p]
    const float* Lb = ws + L_OFF + (size_t)band * CHN * NPIX;
    float4 a0 = make_float4(0.f,0.f,0.f,0.f), a1 = a0, a2 = a0;
#pragma unroll 4
    for (int cg = 0; cg < 16; cg++) {
        int c = cg * 8 + cs;
        float4 lv = *(const float4*)(Lb + (size_t)c * NPIX + n0 + p4);
        float u0 = Us[c][0], u1 = Us[c][1], u2 = Us[c][2];
        a0.x += u0 * lv.x; a0.y += u0 * lv.y; a0.z += u0 * lv.z; a0.w += u0 * lv.w;
        a1.x += u1 * lv.x; a1.y += u1 * lv.y; a1.z += u1 * lv.z; a1.w += u1 * lv.w;
        a2.x += u2 * lv.x; a2.y += u2 * lv.y; a2.z += u2 * lv.z; a2.w += u2 * lv.w;
    }
    *(float4*)&up[cs * 3 + 0][p4] = a0;
    *(float4*)&up[cs * 3 + 1][p4] = a1;
    *(float4*)&up[cs * 3 + 2][p4] = a2;
    __syncthreads();
    if (tid < 96) {
        int r = tid >> 5, p = (tid & 31) * 4;
        float4 s = make_float4(0.f,0.f,0.f,0.f);
#pragma unroll
        for (int g = 0; g < 8; g++) {
            float4 u = *(float4*)&up[g * 3 + r][p];
            s.x += u.x; s.y += u.y; s.z += u.z; s.w += u.w;
        }
        *(float4*)&um[r][p] = s;
    }
    __syncthreads();

    // ---- phase 2: stream x/W/xg, compute UV, losses, L_new (and out at t=9)
    double sw = *(const double*)ws;
    float rho = 0.5f * (float)(sw / (double)NTOT) * alphapow;
    float4 t0 = *(float4*)&um[0][p4];
    float4 t1 = *(float4*)&um[1][p4];
    float4 t2 = *(float4*)&um[2][p4];
    float lf = 0.f, ll = 0.f;
    size_t base = (size_t)band * CHN * NPIX + n0 + p4;
    float* Lp = ws + L_OFF;
#pragma unroll 4
    for (int cg = 0; cg < 16; cg++) {
        int c = cg * 8 + cs;
        size_t idx = base + (size_t)c * NPIX;
        float4 xv = *(const float4*)(x + idx);
        float4 wv = *(const float4*)(W + idx);
        float4 gv = *(const float4*)(xg + idx);
        float u0 = Us[c][0], u1 = Us[c][1], u2 = Us[c][2];
        float4 uv, ln;
        uv.x = u0 * t0.x + u1 * t1.x + u2 * t2.x;
        uv.y = u0 * t0.y + u1 * t1.y + u2 * t2.y;
        uv.z = u0 * t0.z + u1 * t1.z + u2 * t2.z;
        uv.w = u0 * t0.w + u1 * t1.w + u2 * t2.w;
        float dx0 = uv.x - xv.x, dx1 = uv.y - xv.y, dx2 = uv.z - xv.z, dx3 = uv.w - xv.w;
        lf += wv.x * dx0 * dx0 + wv.y * dx1 * dx1 + wv.z * dx2 * dx2 + wv.w * dx3 * dx3;
        float g0 = uv.x - gv.x, g1 = uv.y - gv.y, g2 = uv.z - gv.z, g3 = uv.w - gv.w;
        ll += g0 * g0 + g1 * g1 + g2 * g2 + g3 * g3;
        ln.x = xv.x + (rho / (wv.x + rho)) * dx0;
        ln.y = xv.y + (rho / (wv.y + rho)) * dx1;
        ln.z = xv.z + (rho / (wv.z + rho)) * dx2;
        ln.w = xv.w + (rho / (wv.w + rho)) * dx3;
        *(float4*)(Lp + idx) = ln;
        if (writeUV) *(float4*)(out + idx) = uv;
    }
    for (int o = 32; o > 0; o >>= 1) { lf += __shfl_down(lf, o, 64); ll += __shfl_down(ll, o, 64); }
    if (lane == 0) { red[w] = lf; red[8 + w] = ll; }
    __syncthreads();
    if (tid == 0) {
        float a = red[0] + red[1] + red[2] + red[3];
        float b = red[8] + red[9] + red[10] + red[11];
        atomicAdd((double*)ws + 1 + titer,  (double)a);
        atomicAdd((double*)ws + 11 + titer, (double)b);
    }
}

// ---------------- finalize losses ----------------
__global__ void k_final(float* __restrict__ out, const float* __restrict__ ws) {
    int tid = threadIdx.x;
    const double* d = (const double*)ws;
    if (tid < 10)       out[NTOT + tid] = (float)(d[1 + tid] / (double)NTOT);
    else if (tid < 20)  out[NTOT + tid] = (float)(d[11 + (tid - 10)] / (double)NTOT);
}

extern "C" void kernel_launch(void* const* d_in, const int* in_sizes, int n_in,
                              void* d_out, int out_size, void* d_ws, size_t ws_size,
                              hipStream_t stream) {
    const float* x  = (const float*)d_in[0];
    const float* W  = (const float*)d_in[1];
    const float* xg = (const float*)d_in[2];
    float* out = (float*)d_out;
    float* ws = (float*)d_ws;

    hipMemsetAsync(d_ws, 0, 4096, stream);   // zero scalar/accumulator block
    k_init<<<2048, 256, 0, stream>>>(x, W, ws);

    float ap = 1.0f;
    for (int t = 0; t < 10; t++) {
        k_gram<<<dim3(8, 32), 256, 0, stream>>>(ws);
        k_eig<<<32, 256, 0, stream>>>(ws, t);
        k_upd<<<dim3(32, 32), 256, 0, stream>>>(x, W, xg, out, ws, ap, (t == 9) ? 1 : 0, t);
        ap *= 1.05f;
    }
    k_final<<<1, 64, 0, stream>>>(out, ws);
}

// Round 4
// 1657.527 us; speedup vs baseline: 2.3429x; 1.1472x over previous
//
#include <hip/hip_runtime.h>
#include <stdint.h>

#define BANDS 32
#define CHN   128
#define NPIX  4096
#define NTOT  16777216          // 32*128*4096
#define GSZ   16384             // 128*128
#define KSQ   6                 // squaring stages (G -> G^64, collapse-guarded)

// ---------------- ws layout (float indices) ----------------
// bytes [0..168): doubles: [0]=sumW, [1..10]=lossF acc, [11..20]=loss acc
#define L_OFF    1024
#define GP_OFF   (L_OFF + NTOT)                  // 32*8*16384 gram partials
#define A0_OFF   (GP_OFF + BANDS*8*GSZ)          // (unused now, kept for layout)
#define A1_OFF   (A0_OFF + BANDS*GSZ)
#define U3_OFF   (A1_OFF + BANDS*GSZ)            // 32*128*3
#define VW_OFF   (U3_OFF + BANDS*CHN*3)          // 32*128*8 warm-start basis

typedef short s16x8 __attribute__((ext_vector_type(8)));
typedef float f32x4 __attribute__((ext_vector_type(4)));

__device__ __forceinline__ unsigned short bf16rn(float x) {
    uint32_t u = __float_as_uint(x);
    u += 0x7FFFu + ((u >> 16) & 1u);
    return (unsigned short)(u >> 16);
}
__device__ __forceinline__ float bf16tof(unsigned short h) {
    return __uint_as_float((uint32_t)h << 16);
}

// ---------------- init: L = x, sumW reduction ----------------
__global__ __launch_bounds__(256) void k_init(const float* __restrict__ x,
                                              const float* __restrict__ W,
                                              float* __restrict__ ws) {
    int gid = blockIdx.x * 256 + threadIdx.x;       // 2048*256 threads
    const float4* x4 = (const float4*)x;
    const float4* w4 = (const float4*)W;
    float4* L4 = (float4*)(ws + L_OFF);
    float s = 0.f;
#pragma unroll
    for (int i = 0; i < 8; i++) {
        int idx = gid + i * 524288;                 // NTOT/4 = 4194304
        float4 xv = x4[idx];
        float4 wv = w4[idx];
        L4[idx] = xv;
        s += wv.x + wv.y + wv.z + wv.w;
    }
    for (int o = 32; o > 0; o >>= 1) s += __shfl_down(s, o, 64);
    __shared__ float red[4];
    int wid = threadIdx.x >> 6, lane = threadIdx.x & 63;
    if (lane == 0) red[wid] = s;
    __syncthreads();
    if (threadIdx.x == 0) {
        float t = red[0] + red[1] + red[2] + red[3];
        atomicAdd((double*)ws, (double)t);
    }
}

// ---------------- gram: partial G[b] = L L^T via bf16x2-split MFMA ----------------
// (verified round 2: fragment pattern + C-layout correct on HW)
__global__ __launch_bounds__(256) void k_gram(float* __restrict__ ws) {
    int band = blockIdx.y, kc = blockIdx.x, tid = threadIdx.x;
    __shared__ __align__(16) unsigned short Hs[8192];   // 128x64 bf16 hi, XOR-swizzled
    __shared__ __align__(16) unsigned short Lo[8192];   // lo part
    const float* Lb = ws + L_OFF + (size_t)band * CHN * NPIX;
    int k0 = kc * 512;
    int lane = tid & 63, wv = tid >> 6;
    int wr = (wv >> 1) * 64, wcb = (wv & 1) * 64;
    int l15 = lane & 15, l4g = lane >> 4;

    f32x4 acc[4][4];
#pragma unroll
    for (int m = 0; m < 4; m++)
#pragma unroll
        for (int n = 0; n < 4; n++) acc[m][n] = (f32x4){0.f, 0.f, 0.f, 0.f};

    int srow = tid >> 3, scol = (tid & 7) * 8;          // staging map: 32 rows/pass, 8px chunks

    float4 pre[8];                                       // register prefetch (T14)
#pragma unroll
    for (int p = 0; p < 4; p++) {
        const float* src = Lb + (size_t)(srow + p * 32) * NPIX + k0 + scol;
        pre[2 * p]     = *(const float4*)src;
        pre[2 * p + 1] = *(const float4*)(src + 4);
    }
#pragma unroll 1
    for (int t = 0; t < 8; t++) {                        // 8 K-tiles of 64 px
#pragma unroll
        for (int p = 0; p < 4; p++) {
            int row = srow + p * 32;
            float vv[8] = {pre[2*p].x, pre[2*p].y, pre[2*p].z, pre[2*p].w,
                           pre[2*p+1].x, pre[2*p+1].y, pre[2*p+1].z, pre[2*p+1].w};
            s16x8 hv, lv;
#pragma unroll
            for (int e = 0; e < 8; e++) {
                unsigned short h = bf16rn(vv[e]);
                float r = vv[e] - bf16tof(h);
                hv[e] = (short)h;
                lv[e] = (short)bf16rn(r);
            }
            int off = row * 128 + ((scol * 2) ^ ((row & 7) << 4));
            *(s16x8*)((char*)Hs + off) = hv;
            *(s16x8*)((char*)Lo + off) = lv;
        }
        __syncthreads();
        if (t < 7) {
            int kn = k0 + (t + 1) * 64;
#pragma unroll
            for (int p = 0; p < 4; p++) {
                const float* src = Lb + (size_t)(srow + p * 32) * NPIX + kn + scol;
                pre[2 * p]     = *(const float4*)src;
                pre[2 * p + 1] = *(const float4*)(src + 4);
            }
        }
#pragma unroll
        for (int ks = 0; ks < 2; ks++) {
            int kb2 = ks * 64 + l4g * 16;
            s16x8 Ah[4], Al[4], Bh[4], Bl[4];
#pragma unroll
            for (int m = 0; m < 4; m++) {
                int row = wr + m * 16 + l15;
                int off = row * 128 + (kb2 ^ ((row & 7) << 4));
                Ah[m] = *(const s16x8*)((const char*)Hs + off);
                Al[m] = *(const s16x8*)((const char*)Lo + off);
            }
#pragma unroll
            for (int n = 0; n < 4; n++) {
                int row = wcb + n * 16 + l15;
                int off = row * 128 + (kb2 ^ ((row & 7) << 4));
                Bh[n] = *(const s16x8*)((const char*)Hs + off);
                Bl[n] = *(const s16x8*)((const char*)Lo + off);
            }
#pragma unroll
            for (int m = 0; m < 4; m++)
#pragma unroll
                for (int n = 0; n < 4; n++) {
                    acc[m][n] = __builtin_amdgcn_mfma_f32_16x16x32_bf16(Ah[m], Bh[n], acc[m][n], 0, 0, 0);
                    acc[m][n] = __builtin_amdgcn_mfma_f32_16x16x32_bf16(Ah[m], Bl[n], acc[m][n], 0, 0, 0);
                    acc[m][n] = __builtin_amdgcn_mfma_f32_16x16x32_bf16(Al[m], Bh[n], acc[m][n], 0, 0, 0);
                }
        }
        __syncthreads();
    }
    float* Gp = ws + GP_OFF + (size_t)(band * 8 + kc) * GSZ;
#pragma unroll
    for (int m = 0; m < 4; m++)
#pragma unroll
        for (int n = 0; n < 4; n++) {
            int row0 = wr + m * 16 + l4g * 4;
            int col  = wcb + n * 16 + l15;
#pragma unroll
            for (int r = 0; r < 4; r++)
                Gp[(row0 + r) * 128 + col] = acc[m][n][r];
        }
}

// ---------------- k_eig: fused per-band eigen path, 1024 threads (16 waves) ----------------
// Squaring: bf16x2-split MFMA, 32x32 tile/wave. Subspace matvec W=A*V: MFMA with A's
// Hi/Lo converted once (A fixed during subspace) and V split per step into a padded
// 16-row B operand (rows 8..15 zero). CholQR/RR Gram matrices: 4-wave K-split.
__global__ __launch_bounds__(1024, 4) void k_eig(float* __restrict__ ws, int titer) {
    int band = blockIdx.x, tid = threadIdx.x;
    __shared__ __align__(16) float Aa[128 * 132];            // fp32 A (dead after final convert)
    __shared__ __align__(16) unsigned short HiS[16384];      // bf16 hi, XOR-swizzled 256B rows
    __shared__ __align__(16) unsigned short LoS[16384];      // bf16 lo
    __shared__ __align__(16) unsigned short VhB[2048];       // V^T bf16 hi (16x128, rows 8..15 = 0)
    __shared__ __align__(16) unsigned short VlB[2048];       // V^T bf16 lo
    __shared__ __align__(16) float VcS[8 * 136];
    __shared__ __align__(16) float WcS[8 * 136];
    __shared__ float LchS[64], invdS[8], B8S[64], E8S[64], redS[32], Mpart[256];
    __shared__ int idx3S[3];
    float* WpS = Aa;                       // alias: per-wave matvec partials (16x256 floats)

    int lane = tid & 63, wv = tid >> 6;    // wv 0..15
    int l15 = lane & 15, l4g = lane >> 4;

    // zero pad rows 8..15 of the V operand (written once; cols 8..15 of W never read)
    { int off = (8 + (tid >> 7)) * 128 + (tid & 127);
      VhB[off] = 0; VlB[off] = 0; }

    // ---- load G = sum of 8 gram partials -> Aa, with stats
    const float4* Gp4 = (const float4*)(ws + GP_OFF + (size_t)band * 8 * GSZ);
    float fp = 0.f, tp = 0.f;
#pragma unroll
    for (int rep = 0; rep < 4; rep++) {
        int fi4 = rep * 1024 + tid;
        float4 v = Gp4[fi4];
#pragma unroll
        for (int p = 1; p < 8; p++) {
            float4 u = Gp4[p * 4096 + fi4];
            v.x += u.x; v.y += u.y; v.z += u.z; v.w += u.w;
        }
        int r = fi4 >> 5, c4 = (fi4 & 31) * 4;
        *(float4*)&Aa[r * 132 + c4] = v;
        fp += v.x*v.x + v.y*v.y + v.z*v.z + v.w*v.w;
        int e = r - c4;
        if (e >= 0 && e < 4) tp += (&v.x)[e];
    }
#pragma unroll
    for (int o = 1; o < 64; o <<= 1) { fp += __shfl_xor(fp, o, 64); tp += __shfl_xor(tp, o, 64); }
    if (lane == 0) { redS[wv] = fp; redS[16 + wv] = tp; }
    __syncthreads();
    fp = 0.f; tp = 0.f;
    for (int i = 0; i < 16; i++) { fp += redS[i]; tp += redS[16 + i]; }   // fixed order, uniform

    // ---- squaring chain, in place (tile 32x32 per wave)
    int tr = (wv >> 2) * 32, tc = (wv & 3) * 32;
    for (int j = 0; j < KSQ; j++) {
        if (tp * tp < 3.5f * fp) break;          // uniform across block
        float s2 = 1.0f / fp;
#pragma unroll
        for (int rep = 0; rep < 2; rep++) {
            int idx8 = rep * 1024 + tid;         // 0..2047
            int row = idx8 >> 4, c8 = (idx8 & 15) * 8;
            float4 v0 = *(const float4*)&Aa[row * 132 + c8];
            float4 v1 = *(const float4*)&Aa[row * 132 + c8 + 4];
            float vv[8] = {v0.x, v0.y, v0.z, v0.w, v1.x, v1.y, v1.z, v1.w};
            s16x8 hv, lv;
#pragma unroll
            for (int e = 0; e < 8; e++) {
                unsigned short h = bf16rn(vv[e]);
                float r = vv[e] - bf16tof(h);
                hv[e] = (short)h;
                lv[e] = (short)bf16rn(r);
            }
            int off = row * 256 + ((c8 * 2) ^ ((row & 7) << 4));
            *(s16x8*)((char*)HiS + off) = hv;
            *(s16x8*)((char*)LoS + off) = lv;
        }
        __syncthreads();
        f32x4 acc[2][2];
#pragma unroll
        for (int m = 0; m < 2; m++)
#pragma unroll
            for (int n = 0; n < 2; n++) acc[m][n] = (f32x4){0.f, 0.f, 0.f, 0.f};
#pragma unroll
        for (int ks = 0; ks < 4; ks++) {
            int kb = ks * 64 + l4g * 16;
            s16x8 Ah[2], Al[2], Bh[2], Bl[2];
#pragma unroll
            for (int m = 0; m < 2; m++) {
                int row = tr + m * 16 + l15;
                int off = row * 256 + (kb ^ ((row & 7) << 4));
                Ah[m] = *(const s16x8*)((const char*)HiS + off);
                Al[m] = *(const s16x8*)((const char*)LoS + off);
            }
#pragma unroll
            for (int n = 0; n < 2; n++) {
                int row = tc + n * 16 + l15;
                int off = row * 256 + (kb ^ ((row & 7) << 4));
                Bh[n] = *(const s16x8*)((const char*)HiS + off);
                Bl[n] = *(const s16x8*)((const char*)LoS + off);
            }
#pragma unroll
            for (int m = 0; m < 2; m++)
#pragma unroll
                for (int n = 0; n < 2; n++) {
                    acc[m][n] = __builtin_amdgcn_mfma_f32_16x16x32_bf16(Ah[m], Bh[n], acc[m][n], 0, 0, 0);
                    acc[m][n] = __builtin_amdgcn_mfma_f32_16x16x32_bf16(Ah[m], Bl[n], acc[m][n], 0, 0, 0);
                    acc[m][n] = __builtin_amdgcn_mfma_f32_16x16x32_bf16(Al[m], Bh[n], acc[m][n], 0, 0, 0);
                }
        }
        float nfp = 0.f, ntp = 0.f;
#pragma unroll
        for (int m = 0; m < 2; m++)
#pragma unroll
            for (int n = 0; n < 2; n++)
#pragma unroll
                for (int r = 0; r < 4; r++) {
                    int row = tr + m * 16 + l4g * 4 + r;
                    int col = tc + n * 16 + l15;
                    float val = s2 * acc[m][n][r];
                    Aa[row * 132 + col] = val;
                    nfp += val * val;
                    if (row == col) ntp += val;
                }
#pragma unroll
        for (int o = 1; o < 64; o <<= 1) { nfp += __shfl_xor(nfp, o, 64); ntp += __shfl_xor(ntp, o, 64); }
        if (lane == 0) { redS[wv] = nfp; redS[16 + wv] = ntp; }
        __syncthreads();
        fp = 0.f; tp = 0.f;
        for (int i = 0; i < 16; i++) { fp += redS[i]; tp += redS[16 + i]; }
    }

    // ---- final convert Aa -> Hi/Lo (A is fixed during the subspace loop); Aa then dead
#pragma unroll
    for (int rep = 0; rep < 2; rep++) {
        int idx8 = rep * 1024 + tid;
        int row = idx8 >> 4, c8 = (idx8 & 15) * 8;
        float4 v0 = *(const float4*)&Aa[row * 132 + c8];
        float4 v1 = *(const float4*)&Aa[row * 132 + c8 + 4];
        float vv[8] = {v0.x, v0.y, v0.z, v0.w, v1.x, v1.y, v1.z, v1.w};
        s16x8 hv, lv;
#pragma unroll
        for (int e = 0; e < 8; e++) {
            unsigned short h = bf16rn(vv[e]);
            float r = vv[e] - bf16tof(h);
            hv[e] = (short)h;
            lv[e] = (short)bf16rn(r);
        }
        int off = row * 256 + ((c8 * 2) ^ ((row & 7) << 4));
        *(s16x8*)((char*)HiS + off) = hv;
        *(s16x8*)((char*)LoS + off) = lv;
    }
    __syncthreads();

    // ---- V init / warm start
    if (titer == 0) {
        for (int idx = tid; idx < 1024; idx += 1024) {
            uint32_t h = (uint32_t)(idx + band * 1024 + 7) * 2654435761u;
            h ^= h >> 15; h *= 0x2c1b3c6du; h ^= h >> 12;
            VcS[(idx >> 7) * 136 + (idx & 127)] = ((float)(h & 0xFFFF) / 32768.0f) - 1.0f;
        }
    } else {
        for (int idx = tid; idx < 1024; idx += 1024)
            VcS[(idx >> 7) * 136 + (idx & 127)] = ws[VW_OFF + band * 1024 + idx];
    }
    __syncthreads();

    int steps = (titer == 0) ? 8 : 4;
    int mt = wv >> 1, kh = wv & 1;             // matvec wave mapping
    int rr = (tid & 63) >> 3, ss = tid & 7;    // 8x8 pair mapping (waves 0..3 K-split)

    for (int step = 0; step <= steps; step++) {
        // ---- V -> bf16 split into padded B operand (rows 0..7)
        if (tid < 512) {
            int jj = tid >> 6, k0 = (tid & 63) * 2;
            float v0 = VcS[jj * 136 + k0], v1 = VcS[jj * 136 + k0 + 1];
            unsigned short h0 = bf16rn(v0); float r0 = v0 - bf16tof(h0);
            unsigned short h1 = bf16rn(v1); float r1 = v1 - bf16tof(h1);
            int boff = jj * 256 + ((k0 * 2) ^ ((jj & 7) << 4));
            *(ushort2*)((char*)VhB + boff) = make_ushort2(h0, h1);
            *(ushort2*)((char*)VlB + boff) = make_ushort2(bf16rn(r0), bf16rn(r1));
        }
        __syncthreads();
        // ---- W = A * V via MFMA: wave (mt, kh) does rows mt*16..+15, K-half kh
        f32x4 acc = (f32x4){0.f, 0.f, 0.f, 0.f};
#pragma unroll
        for (int kq = 0; kq < 2; kq++) {
            int kb = (kh * 2 + kq) * 64 + l4g * 16;
            int ar = mt * 16 + l15;
            int aoff = ar * 256 + (kb ^ ((ar & 7) << 4));
            s16x8 Ah = *(const s16x8*)((const char*)HiS + aoff);
            s16x8 Al = *(const s16x8*)((const char*)LoS + aoff);
            int boff = l15 * 256 + (kb ^ ((l15 & 7) << 4));
            s16x8 Bh = *(const s16x8*)((const char*)VhB + boff);
            s16x8 Bl = *(const s16x8*)((const char*)VlB + boff);
            acc = __builtin_amdgcn_mfma_f32_16x16x32_bf16(Ah, Bh, acc, 0, 0, 0);
            acc = __builtin_amdgcn_mfma_f32_16x16x32_bf16(Ah, Bl, acc, 0, 0, 0);
            acc = __builtin_amdgcn_mfma_f32_16x16x32_bf16(Al, Bh, acc, 0, 0, 0);
        }
        *(f32x4*)&WpS[wv * 256 + lane * 4] = acc;
        __syncthreads();
        // ---- combine K-halves -> WcS[col][row] (column-major, stride 136)
        {
            int mt2 = tid >> 7, rem = tid & 127;
            int col = rem & 7, r = (rem >> 3) & 3, g4 = rem >> 5;
            int lidx = (g4 * 16 + col) * 4 + r;
            float wval = WpS[(2 * mt2) * 256 + lidx] + WpS[(2 * mt2 + 1) * 256 + lidx];
            WcS[col * 136 + mt2 * 16 + g4 * 4 + r] = wval;
        }
        __syncthreads();
        if (step == steps) break;

        // ---- CholQR: M = W^T W, K-split over waves 0..3
        if (tid < 256) {
            const float* wrp = WcS + rr * 136 + wv * 32;
            const float* wcp = WcS + ss * 136 + wv * 32;
            float m = 0.f;
#pragma unroll
            for (int k = 0; k < 32; k += 4) {
                float4 p = *(const float4*)&wrp[k];
                float4 q = *(const float4*)&wcp[k];
                m += p.x * q.x + p.y * q.y + p.z * q.z + p.w * q.w;
            }
            Mpart[wv * 64 + (tid & 63)] = m;
        }
        __syncthreads();
        if (tid < 64) {
            float m = (Mpart[tid] + Mpart[64 + tid]) + (Mpart[128 + tid] + Mpart[192 + tid]);
            int r8 = tid >> 3, s8 = tid & 7;
            float t = (r8 == s8) ? m : 0.f;
#pragma unroll
            for (int o = 1; o < 64; o <<= 1) t += __shfl_xor(t, o, 64);
            float eps = 1e-12f * t + 1e-35f;
            float v = m;
#pragma unroll
            for (int j = 0; j < 8; j++) {
                float dj = __shfl(v, j * 9, 64);
                dj = fmaxf(dj, eps);
                float lj = sqrtf(dj);
                float inv = 1.f / lj;
                if (s8 == j) v = (r8 == j) ? lj : (r8 > j ? v * inv : v);
                float Lr = __shfl(v, r8 * 8 + j, 64);
                float Ls = __shfl(v, s8 * 8 + j, 64);
                if (r8 > j && s8 > j) v -= Lr * Ls;
                if (tid == j) invdS[j] = inv;
            }
            LchS[tid] = v;
        }
        __syncthreads();
        // ---- backsolve V = W L^-T (tid<128)
        if (tid < 128) {
            float w[8], vv[8];
#pragma unroll
            for (int s = 0; s < 8; s++) w[s] = WcS[s * 136 + tid];
#pragma unroll
            for (int s = 0; s < 8; s++) {
                float t2 = w[s];
                for (int j = 0; j < s; j++) t2 -= vv[j] * LchS[s * 8 + j];
                vv[s] = t2 * invdS[s];
                VcS[s * 136 + tid] = vv[s];
            }
        }
        __syncthreads();
    }

    // ---- Rayleigh-Ritz: B = V^T W, K-split over waves 0..3
    if (tid < 256) {
        const float* vr = VcS + rr * 136 + wv * 32;
        const float* wcp = WcS + ss * 136 + wv * 32;
        float m = 0.f;
#pragma unroll
        for (int k = 0; k < 32; k += 4) {
            float4 p = *(const float4*)&vr[k];
            float4 q = *(const float4*)&wcp[k];
            m += p.x * q.x + p.y * q.y + p.z * q.z + p.w * q.w;
        }
        Mpart[wv * 64 + (tid & 63)] = m;
    }
    __syncthreads();
    if (tid < 64) {
        int r8 = tid >> 3, s8 = tid & 7;
        float m = (Mpart[tid] + Mpart[64 + tid]) + (Mpart[128 + tid] + Mpart[192 + tid]);
        float mT = __shfl(m, s8 * 8 + r8, 64);      // symmetrize via shuffle
        float b = 0.5f * (m + mT);
        float e = (r8 == s8) ? 1.f : 0.f;

        for (int sweep = 0; sweep < 6; sweep++) {
            for (int rd = 0; rd < 7; rd++) {
                int pr = (r8 == 7) ? rd : ((r8 == rd) ? 7 : (2 * rd + 7 - r8) % 7);
                int pc = (s8 == 7) ? rd : ((s8 == rd) ? 7 : (2 * rd + 7 - s8) % 7);
                int P = min(r8, pr), Q = max(r8, pr);
                int Pc = min(s8, pc), Qc = max(s8, pc);
                float app = __shfl(b, P * 9, 64);
                float aqq = __shfl(b, Q * 9, 64);
                float apq = __shfl(b, P * 8 + Q, 64);
                float cR, sR;
                if (fabsf(apq) < 1e-28f) { cR = 1.f; sR = 0.f; }
                else {
                    float tau = (aqq - app) / (2.f * apq);
                    float tt = ((tau >= 0.f) ? 1.f : -1.f) / (fabsf(tau) + sqrtf(1.f + tau * tau));
                    cR = rsqrtf(1.f + tt * tt); sR = tt * cR;
                }
                float ap2 = __shfl(b, Pc * 9, 64);
                float aq2 = __shfl(b, Qc * 9, 64);
                float apq2 = __shfl(b, Pc * 8 + Qc, 64);
                float cC, sC;
                if (fabsf(apq2) < 1e-28f) { cC = 1.f; sC = 0.f; }
                else {
                    float tau = (aq2 - ap2) / (2.f * apq2);
                    float tt = ((tau >= 0.f) ? 1.f : -1.f) / (fabsf(tau) + sqrtf(1.f + tau * tau));
                    cC = rsqrtf(1.f + tt * tt); sC = tt * cC;
                }
                float tv = __shfl(b, pr * 8 + s8, 64);
                float bn = (r8 < pr) ? (cR * b - sR * tv) : (sR * tv + cR * b);
                float t2 = __shfl(bn, r8 * 8 + pc, 64);
                b = (s8 < pc) ? (cC * bn - sC * t2) : (sC * t2 + cC * bn);
                float e2 = __shfl(e, r8 * 8 + pc, 64);
                e = (s8 < pc) ? (cC * e - sC * e2) : (sC * e2 + cC * e);
            }
        }
        B8S[tid] = b;
        E8S[tid] = e;
        if (tid == 0) {
            int used = 0;
            for (int r = 0; r < 3; r++) {
                int best = 0; float bv = -1e38f;
                for (int s = 0; s < 8; s++)
                    if (!(used & (1 << s)) && B8S[s * 9] > bv) { bv = B8S[s * 9]; best = s; }
                used |= 1 << best;
                idx3S[r] = best;
            }
        }
    }
    __syncthreads();

    // ---- U = V * E[:, idx3], warm-start save
    if (tid < 128) {
        float e[3][8];
#pragma unroll
        for (int r = 0; r < 3; r++)
#pragma unroll
            for (int s = 0; s < 8; s++) e[r][s] = E8S[s * 8 + idx3S[r]];
        float vcl[8];
#pragma unroll
        for (int s = 0; s < 8; s++) vcl[s] = VcS[s * 136 + tid];
#pragma unroll
        for (int r = 0; r < 3; r++) {
            float u = 0.f;
#pragma unroll
            for (int s = 0; s < 8; s++) u += vcl[s] * e[r][s];
            ws[U3_OFF + band * 384 + tid * 3 + r] = u;
        }
#pragma unroll
        for (int s = 0; s < 8; s++) ws[VW_OFF + band * 1024 + s * 128 + tid] = vcl[s];
    }
}

// ---------------- fused: utl = U^T L (phase 1) + UV/losses/L_new (phase 2) ----------------
__global__ __launch_bounds__(256) void k_upd(const float* __restrict__ x,
                                             const float* __restrict__ W,
                                             const float* __restrict__ xg,
                                             float* __restrict__ out,
                                             float* __restrict__ ws,
                                             float alphapow, int writeUV, int titer) {
    int band = blockIdx.y, xc = blockIdx.x, tid = threadIdx.x;
    int w = tid >> 6, lane = tid & 63;
    int half = lane >> 5, l32 = lane & 31;
    int n0 = xc * 128, p4 = l32 * 4;
    int cs = w * 2 + half;                       // 0..7
    __shared__ float Us[128][4];
    __shared__ __align__(16) float up[24][132];  // partials [cs*3+r][px]
    __shared__ __align__(16) float um[3][132];   // reduced utl
    __shared__ float red[16];

    if (tid < 128) {
        Us[tid][0] = ws[U3_OFF + band * 384 + tid * 3 + 0];
        Us[tid][1] = ws[U3_OFF + band * 384 + tid * 3 + 1];
        Us[tid][2] = ws[U3_OFF + band * 384 + tid * 3 + 2];
    }
    __syncthreads();

    // ---- phase 1: utl[r][p] = sum_c U[c][r] * L[c][p]
    const float* Lb = ws + L_OFF + (size_t)band * CHN * NPIX;
    float4 a0 = make_float4(0.f,0.f,0.f,0.f), a1 = a0, a2 = a0;
#pragma unroll 4
    for (int cg = 0; cg < 16; cg++) {
        int c = cg * 8 + cs;
        float4 lv = *(const float4*)(Lb + (size_t)c * NPIX + n0 + p4);
        float u0 = Us[c][0], u1 = Us[c][1], u2 = Us[c][2];
        a0.x += u0 * lv.x; a0.y += u0 * lv.y; a0.z += u0 * lv.z; a0.w += u0 * lv.w;
        a1.x += u1 * lv.x; a1.y += u1 * lv.y; a1.z += u1 * lv.z; a1.w += u1 * lv.w;
        a2.x += u2 * lv.x; a2.y += u2 * lv.y; a2.z += u2 * lv.z; a2.w += u2 * lv.w;
    }
    *(float4*)&up[cs * 3 + 0][p4] = a0;
    *(float4*)&up[cs * 3 + 1][p4] = a1;
    *(float4*)&up[cs * 3 + 2][p4] = a2;
    __syncthreads();
    if (tid < 96) {
        int r = tid >> 5, p = (tid & 31) * 4;
        float4 s = make_float4(0.f,0.f,0.f,0.f);
#pragma unroll
        for (int g = 0; g < 8; g++) {
            float4 u = *(float4*)&up[g * 3 + r][p];
            s.x += u.x; s.y += u.y; s.z += u.z; s.w += u.w;
        }
        *(float4*)&um[r][p] = s;
    }
    __syncthreads();

    // ---- phase 2: stream x/W/xg, compute UV, losses, L_new (and out at t=9)
    double sw = *(const double*)ws;
    float rho = 0.5f * (float)(sw / (double)NTOT) * alphapow;
    float4 t0 = *(float4*)&um[0][p4];
    float4 t1 = *(float4*)&um[1][p4];
    float4 t2 = *(float4*)&um[2][p4];
    float lf = 0.f, ll = 0.f;
    size_t base = (size_t)band * CHN * NPIX + n0 + p4;
    float* Lp = ws + L_OFF;
#pragma unroll 4
    for (int cg = 0; cg < 16; cg++) {
        int c = cg * 8 + cs;
        size_t idx = base + (size_t)c * NPIX;
        float4 xv = *(const float4*)(x + idx);
        float4 wv = *(const float4*)(W + idx);
        float4 gv = *(const float4*)(xg + idx);
        float u0 = Us[c][0], u1 = Us[c][1], u2 = Us[c][2];
        float4 uv, ln;
        uv.x = u0 * t0.x + u1 * t1.x + u2 * t2.x;
        uv.y = u0 * t0.y + u1 * t1.y + u2 * t2.y;
        uv.z = u0 * t0.z + u1 * t1.z + u2 * t2.z;
        uv.w = u0 * t0.w + u1 * t1.w + u2 * t2.w;
        float dx0 = uv.x - xv.x, dx1 = uv.y - xv.y, dx2 = uv.z - xv.z, dx3 = uv.w - xv.w;
        lf += wv.x * dx0 * dx0 + wv.y * dx1 * dx1 + wv.z * dx2 * dx2 + wv.w * dx3 * dx3;
        float g0 = uv.x - gv.x, g1 = uv.y - gv.y, g2 = uv.z - gv.z, g3 = uv.w - gv.w;
        ll += g0 * g0 + g1 * g1 + g2 * g2 + g3 * g3;
        ln.x = xv.x + (rho / (wv.x + rho)) * dx0;
        ln.y = xv.y + (rho / (wv.y + rho)) * dx1;
        ln.z = xv.z + (rho / (wv.z + rho)) * dx2;
        ln.w = xv.w + (rho / (wv.w + rho)) * dx3;
        *(float4*)(Lp + idx) = ln;
        if (writeUV) *(float4*)(out + idx) = uv;
    }
    for (int o = 32; o > 0; o >>= 1) { lf += __shfl_down(lf, o, 64); ll += __shfl_down(ll, o, 64); }
    if (lane == 0) { red[w] = lf; red[8 + w] = ll; }
    __syncthreads();
    if (tid == 0) {
        float a = red[0] + red[1] + red[2] + red[3];
        float b = red[8] + red[9] + red[10] + red[11];
        atomicAdd((double*)ws + 1 + titer,  (double)a);
        atomicAdd((double*)ws + 11 + titer, (double)b);
    }
}

// ---------------- finalize losses ----------------
__global__ void k_final(float* __restrict__ out, const float* __restrict__ ws) {
    int tid = threadIdx.x;
    const double* d = (const double*)ws;
    if (tid < 10)       out[NTOT + tid] = (float)(d[1 + tid] / (double)NTOT);
    else if (tid < 20)  out[NTOT + tid] = (float)(d[11 + (tid - 10)] / (double)NTOT);
}

extern "C" void kernel_launch(void* const* d_in, const int* in_sizes, int n_in,
                              void* d_out, int out_size, void* d_ws, size_t ws_size,
                              hipStream_t stream) {
    const float* x  = (const float*)d_in[0];
    const float* W  = (const float*)d_in[1];
    const float* xg = (const float*)d_in[2];
    float* out = (float*)d_out;
    float* ws = (float*)d_ws;

    hipMemsetAsync(d_ws, 0, 4096, stream);   // zero scalar/accumulator block
    k_init<<<2048, 256, 0, stream>>>(x, W, ws);

    float ap = 1.0f;
    for (int t = 0; t < 10; t++) {
        k_gram<<<dim3(8, 32), 256, 0, stream>>>(ws);
        k_eig<<<32, 1024, 0, stream>>>(ws, t);
        k_upd<<<dim3(32, 32), 256, 0, stream>>>(x, W, xg, out, ws, ap, (t == 9) ? 1 : 0, t);
        ap *= 1.05f;
    }
    k_final<<<1, 64, 0, stream>>>(out, ws);
}

// Round 5
// 1545.759 us; speedup vs baseline: 2.5124x; 1.0723x over previous
//
#include <hip/hip_runtime.h>
#include <stdint.h>

#define BANDS 32
#define CHN   128
#define NPIX  4096
#define NTOT  16777216          // 32*128*4096
#define GSZ   16384             // 128*128
#define KSQ   6                 // squaring stages (G -> G^64, collapse-guarded)

// ---------------- ws layout (float indices) ----------------
// doubles: [0]=sumW; loss banks: lossF d[24+t*8+k], loss d[104+t*8+k] (k=0..7)
#define L_OFF    1024
#define GP_OFF   (L_OFF + NTOT)                  // 32*8*16384 gram partials
#define A0_OFF   (GP_OFF + BANDS*8*GSZ)          // summed G per band
#define A1_OFF   (A0_OFF + BANDS*GSZ)
#define U3_OFF   (A1_OFF + BANDS*GSZ)            // 32*128*3
#define VW_OFF   (U3_OFF + BANDS*CHN*3)          // 32*128*8 warm-start basis

typedef short s16x8 __attribute__((ext_vector_type(8)));
typedef float f32x4 __attribute__((ext_vector_type(4)));

__device__ __forceinline__ unsigned short bf16rn(float x) {
    uint32_t u = __float_as_uint(x);
    u += 0x7FFFu + ((u >> 16) & 1u);
    return (unsigned short)(u >> 16);
}
__device__ __forceinline__ float bf16tof(unsigned short h) {
    return __uint_as_float((uint32_t)h << 16);
}

// ---------------- init: L = x, sumW reduction ----------------
__global__ __launch_bounds__(256) void k_init(const float* __restrict__ x,
                                              const float* __restrict__ W,
                                              float* __restrict__ ws) {
    int gid = blockIdx.x * 256 + threadIdx.x;       // 2048*256 threads
    const float4* x4 = (const float4*)x;
    const float4* w4 = (const float4*)W;
    float4* L4 = (float4*)(ws + L_OFF);
    float s = 0.f;
#pragma unroll
    for (int i = 0; i < 8; i++) {
        int idx = gid + i * 524288;                 // NTOT/4 = 4194304
        float4 xv = x4[idx];
        float4 wv = w4[idx];
        L4[idx] = xv;
        s += wv.x + wv.y + wv.z + wv.w;
    }
    for (int o = 32; o > 0; o >>= 1) s += __shfl_down(s, o, 64);
    __shared__ float red[4];
    int wid = threadIdx.x >> 6, lane = threadIdx.x & 63;
    if (lane == 0) red[wid] = s;
    __syncthreads();
    if (threadIdx.x == 0) {
        float t = red[0] + red[1] + red[2] + red[3];
        atomicAdd((double*)ws, (double)t);
    }
}

// ---------------- gram: partial G[b] = L L^T via bf16x2-split MFMA ----------------
__global__ __launch_bounds__(256) void k_gram(float* __restrict__ ws) {
    int band = blockIdx.y, kc = blockIdx.x, tid = threadIdx.x;
    __shared__ __align__(16) unsigned short Hs[8192];   // 128x64 bf16 hi, XOR-swizzled
    __shared__ __align__(16) unsigned short Lo[8192];   // lo part
    const float* Lb = ws + L_OFF + (size_t)band * CHN * NPIX;
    int k0 = kc * 512;
    int lane = tid & 63, wv = tid >> 6;
    int wr = (wv >> 1) * 64, wcb = (wv & 1) * 64;
    int l15 = lane & 15, l4g = lane >> 4;

    f32x4 acc[4][4];
#pragma unroll
    for (int m = 0; m < 4; m++)
#pragma unroll
        for (int n = 0; n < 4; n++) acc[m][n] = (f32x4){0.f, 0.f, 0.f, 0.f};

    int srow = tid >> 3, scol = (tid & 7) * 8;

    float4 pre[8];
#pragma unroll
    for (int p = 0; p < 4; p++) {
        const float* src = Lb + (size_t)(srow + p * 32) * NPIX + k0 + scol;
        pre[2 * p]     = *(const float4*)src;
        pre[2 * p + 1] = *(const float4*)(src + 4);
    }
#pragma unroll 1
    for (int t = 0; t < 8; t++) {
#pragma unroll
        for (int p = 0; p < 4; p++) {
            int row = srow + p * 32;
            float vv[8] = {pre[2*p].x, pre[2*p].y, pre[2*p].z, pre[2*p].w,
                           pre[2*p+1].x, pre[2*p+1].y, pre[2*p+1].z, pre[2*p+1].w};
            s16x8 hv, lv;
#pragma unroll
            for (int e = 0; e < 8; e++) {
                unsigned short h = bf16rn(vv[e]);
                float r = vv[e] - bf16tof(h);
                hv[e] = (short)h;
                lv[e] = (short)bf16rn(r);
            }
            int off = row * 128 + ((scol * 2) ^ ((row & 7) << 4));
            *(s16x8*)((char*)Hs + off) = hv;
            *(s16x8*)((char*)Lo + off) = lv;
        }
        __syncthreads();
        if (t < 7) {
            int kn = k0 + (t + 1) * 64;
#pragma unroll
            for (int p = 0; p < 4; p++) {
                const float* src = Lb + (size_t)(srow + p * 32) * NPIX + kn + scol;
                pre[2 * p]     = *(const float4*)src;
                pre[2 * p + 1] = *(const float4*)(src + 4);
            }
        }
#pragma unroll
        for (int ks = 0; ks < 2; ks++) {
            int kb2 = ks * 64 + l4g * 16;
            s16x8 Ah[4], Al[4], Bh[4], Bl[4];
#pragma unroll
            for (int m = 0; m < 4; m++) {
                int row = wr + m * 16 + l15;
                int off = row * 128 + (kb2 ^ ((row & 7) << 4));
                Ah[m] = *(const s16x8*)((const char*)Hs + off);
                Al[m] = *(const s16x8*)((const char*)Lo + off);
            }
#pragma unroll
            for (int n = 0; n < 4; n++) {
                int row = wcb + n * 16 + l15;
                int off = row * 128 + (kb2 ^ ((row & 7) << 4));
                Bh[n] = *(const s16x8*)((const char*)Hs + off);
                Bl[n] = *(const s16x8*)((const char*)Lo + off);
            }
#pragma unroll
            for (int m = 0; m < 4; m++)
#pragma unroll
                for (int n = 0; n < 4; n++) {
                    acc[m][n] = __builtin_amdgcn_mfma_f32_16x16x32_bf16(Ah[m], Bh[n], acc[m][n], 0, 0, 0);
                    acc[m][n] = __builtin_amdgcn_mfma_f32_16x16x32_bf16(Ah[m], Bl[n], acc[m][n], 0, 0, 0);
                    acc[m][n] = __builtin_amdgcn_mfma_f32_16x16x32_bf16(Al[m], Bh[n], acc[m][n], 0, 0, 0);
                }
        }
        __syncthreads();
    }
    float* Gp = ws + GP_OFF + (size_t)(band * 8 + kc) * GSZ;
#pragma unroll
    for (int m = 0; m < 4; m++)
#pragma unroll
        for (int n = 0; n < 4; n++) {
            int row0 = wr + m * 16 + l4g * 4;
            int col  = wcb + n * 16 + l15;
#pragma unroll
            for (int r = 0; r < 4; r++)
                Gp[(row0 + r) * 128 + col] = acc[m][n][r];
        }
}

// ---------------- redG: sum 8 gram partials at full-chip BW ----------------
__global__ __launch_bounds__(256) void k_redG(float* __restrict__ ws) {
    int b = blockIdx.x >> 3, seg = blockIdx.x & 7, tid = threadIdx.x;
    const float4* src = (const float4*)(ws + GP_OFF + (size_t)b * 8 * GSZ);
    float4* dst = (float4*)(ws + A0_OFF + (size_t)b * GSZ);
#pragma unroll
    for (int rep = 0; rep < 2; rep++) {
        int fi4 = seg * 512 + rep * 256 + tid;
        float4 v = src[fi4];
#pragma unroll
        for (int p = 1; p < 8; p++) {
            float4 u = src[p * 4096 + fi4];
            v.x += u.x; v.y += u.y; v.z += u.z; v.w += u.w;
        }
        dst[fi4] = v;
    }
}

// ---------------- k_eig: fused per-band eigen path, 1024 threads ----------------
// Squaring: double-buffered bf16 Hi/Lo (no fp32 matrix): MFMA from buf[cur],
// writeback scales + stats + converts to Hi/Lo into buf[nxt]; 1 barrier/stage.
// Matvec: 8 waves, full K=128, direct WcS write; V-convert folded into backsolve.
__global__ __launch_bounds__(1024, 4) void k_eig(float* __restrict__ ws, int titer) {
    int band = blockIdx.x, tid = threadIdx.x;
    __shared__ __align__(16) unsigned short HiA[16384], LoA[16384];
    __shared__ __align__(16) unsigned short HiB[16384], LoB[16384];
    __shared__ __align__(16) unsigned short VhB[2048], VlB[2048];  // V^T bf16 (16x128, rows 8..15=0)
    __shared__ __align__(16) float VcS[8 * 136];
    __shared__ __align__(16) float WcS[8 * 136];
    __shared__ float LchS[64], invdS[8], B8S[64], E8S[64], redS[32], Mpart[256];
    __shared__ int idx3S[3];

    int lane = tid & 63, wv = tid >> 6;
    int l15 = lane & 15, l4g = lane >> 4;

    // zero pad rows 8..15 of the V operand (swizzle permutes within-row: zeros ok)
    { int off = (8 + (tid >> 7)) * 128 + (tid & 127);
      VhB[off] = 0; VlB[off] = 0; }

    // ---- load summed G -> Hi/Lo directly, with stats
    const float4* G4 = (const float4*)(ws + A0_OFF + (size_t)band * GSZ);
    float fp = 0.f, tp = 0.f;
#pragma unroll
    for (int rep = 0; rep < 4; rep++) {
        int fi4 = rep * 1024 + tid;
        float4 v = G4[fi4];
        int r = fi4 >> 5, c4 = (fi4 & 31) * 4;
        fp += v.x*v.x + v.y*v.y + v.z*v.z + v.w*v.w;
        int e = r - c4;
        if (e >= 0 && e < 4) tp += (&v.x)[e];
        float vv[4] = {v.x, v.y, v.z, v.w};
        ushort4 hv, lv;
        unsigned short h;
        h = bf16rn(vv[0]); hv.x = h; lv.x = bf16rn(vv[0] - bf16tof(h));
        h = bf16rn(vv[1]); hv.y = h; lv.y = bf16rn(vv[1] - bf16tof(h));
        h = bf16rn(vv[2]); hv.z = h; lv.z = bf16rn(vv[2] - bf16tof(h));
        h = bf16rn(vv[3]); hv.w = h; lv.w = bf16rn(vv[3] - bf16tof(h));
        int off = r * 256 + ((c4 * 2) ^ ((r & 7) << 4));
        *(ushort4*)((char*)HiA + off) = hv;
        *(ushort4*)((char*)LoA + off) = lv;
    }
#pragma unroll
    for (int o = 1; o < 64; o <<= 1) { fp += __shfl_xor(fp, o, 64); tp += __shfl_xor(tp, o, 64); }
    if (lane == 0) { redS[wv] = fp; redS[16 + wv] = tp; }
    __syncthreads();
    fp = 0.f; tp = 0.f;
    for (int i = 0; i < 16; i++) { fp += redS[i]; tp += redS[16 + i]; }   // fixed order, uniform

    // ---- squaring chain, double-buffered Hi/Lo
    unsigned short *Hc = HiA, *Lc = LoA, *Hn = HiB, *Ln = LoB;
    int tr = (wv >> 2) * 32, tc = (wv & 3) * 32;
    for (int j = 0; j < KSQ; j++) {
        if (tp * tp < 3.5f * fp) break;          // uniform across block
        float s2 = 1.0f / fp;
        f32x4 acc[2][2];
#pragma unroll
        for (int m = 0; m < 2; m++)
#pragma unroll
            for (int n = 0; n < 2; n++) acc[m][n] = (f32x4){0.f, 0.f, 0.f, 0.f};
#pragma unroll
        for (int ks = 0; ks < 4; ks++) {
            int kb = ks * 64 + l4g * 16;
            s16x8 Ah[2], Al[2], Bh[2], Bl[2];
#pragma unroll
            for (int m = 0; m < 2; m++) {
                int row = tr + m * 16 + l15;
                int off = row * 256 + (kb ^ ((row & 7) << 4));
                Ah[m] = *(const s16x8*)((const char*)Hc + off);
                Al[m] = *(const s16x8*)((const char*)Lc + off);
            }
#pragma unroll
            for (int n = 0; n < 2; n++) {
                int row = tc + n * 16 + l15;
                int off = row * 256 + (kb ^ ((row & 7) << 4));
                Bh[n] = *(const s16x8*)((const char*)Hc + off);
                Bl[n] = *(const s16x8*)((const char*)Lc + off);
            }
#pragma unroll
            for (int m = 0; m < 2; m++)
#pragma unroll
                for (int n = 0; n < 2; n++) {
                    acc[m][n] = __builtin_amdgcn_mfma_f32_16x16x32_bf16(Ah[m], Bh[n], acc[m][n], 0, 0, 0);
                    acc[m][n] = __builtin_amdgcn_mfma_f32_16x16x32_bf16(Ah[m], Bl[n], acc[m][n], 0, 0, 0);
                    acc[m][n] = __builtin_amdgcn_mfma_f32_16x16x32_bf16(Al[m], Bh[n], acc[m][n], 0, 0, 0);
                }
        }
        float nfp = 0.f, ntp = 0.f;
#pragma unroll
        for (int m = 0; m < 2; m++)
#pragma unroll
            for (int n = 0; n < 2; n++)
#pragma unroll
                for (int r = 0; r < 4; r++) {
                    int row = tr + m * 16 + l4g * 4 + r;
                    int col = tc + n * 16 + l15;
                    float val = s2 * acc[m][n][r];
                    nfp += val * val;
                    if (row == col) ntp += val;
                    unsigned short h = bf16rn(val);
                    unsigned short lo = bf16rn(val - bf16tof(h));
                    int off = row * 256 + ((col * 2) ^ ((row & 7) << 4));
                    *(unsigned short*)((char*)Hn + off) = h;
                    *(unsigned short*)((char*)Ln + off) = lo;
                }
#pragma unroll
        for (int o = 1; o < 64; o <<= 1) { nfp += __shfl_xor(nfp, o, 64); ntp += __shfl_xor(ntp, o, 64); }
        if (lane == 0) { redS[wv] = nfp; redS[16 + wv] = ntp; }
        __syncthreads();
        fp = 0.f; tp = 0.f;
        for (int i = 0; i < 16; i++) { fp += redS[i]; tp += redS[16 + i]; }
        unsigned short* t1 = Hc; Hc = Hn; Hn = t1;
        unsigned short* t2 = Lc; Lc = Ln; Ln = t2;
    }

    // ---- V init / warm start
    if (titer == 0) {
        uint32_t h = (uint32_t)(tid + band * 1024 + 7) * 2654435761u;
        h ^= h >> 15; h *= 0x2c1b3c6du; h ^= h >> 12;
        VcS[(tid >> 7) * 136 + (tid & 127)] = ((float)(h & 0xFFFF) / 32768.0f) - 1.0f;
    } else {
        VcS[(tid >> 7) * 136 + (tid & 127)] = ws[VW_OFF + band * 1024 + tid];
    }
    __syncthreads();
    if (tid < 512) {                              // initial V -> bf16 operand
        int jj = tid >> 6, k0 = (tid & 63) * 2;
        float v0 = VcS[jj * 136 + k0], v1 = VcS[jj * 136 + k0 + 1];
        unsigned short h0 = bf16rn(v0); float r0 = v0 - bf16tof(h0);
        unsigned short h1 = bf16rn(v1); float r1 = v1 - bf16tof(h1);
        int boff = jj * 256 + ((k0 * 2) ^ ((jj & 7) << 4));
        *(ushort2*)((char*)VhB + boff) = make_ushort2(h0, h1);
        *(ushort2*)((char*)VlB + boff) = make_ushort2(bf16rn(r0), bf16rn(r1));
    }
    __syncthreads();

    int steps = (titer == 0) ? 8 : 4;
    int rr = (tid & 63) >> 3, ss = tid & 7;

    for (int step = 0; step <= steps; step++) {
        // ---- W = A * V via MFMA: wave wv (<8) does rows wv*16..+15, full K
        if (wv < 8) {
            f32x4 acc = (f32x4){0.f, 0.f, 0.f, 0.f};
            int ar = wv * 16 + l15;
#pragma unroll
            for (int kq = 0; kq < 4; kq++) {
                int kb = kq * 64 + l4g * 16;
                int aoff = ar * 256 + (kb ^ ((ar & 7) << 4));
                s16x8 Ah = *(const s16x8*)((const char*)Hc + aoff);
                s16x8 Al = *(const s16x8*)((const char*)Lc + aoff);
                int boff = l15 * 256 + (kb ^ ((l15 & 7) << 4));
                s16x8 Bh = *(const s16x8*)((const char*)VhB + boff);
                s16x8 Bl = *(const s16x8*)((const char*)VlB + boff);
                acc = __builtin_amdgcn_mfma_f32_16x16x32_bf16(Ah, Bh, acc, 0, 0, 0);
                acc = __builtin_amdgcn_mfma_f32_16x16x32_bf16(Ah, Bl, acc, 0, 0, 0);
                acc = __builtin_amdgcn_mfma_f32_16x16x32_bf16(Al, Bh, acc, 0, 0, 0);
            }
            if (l15 < 8) {
#pragma unroll
                for (int r = 0; r < 4; r++)
                    WcS[l15 * 136 + wv * 16 + l4g * 4 + r] = acc[r];
            }
        }
        __syncthreads();
        if (step == steps) break;

        // ---- CholQR: M = W^T W, K-split over waves 0..3
        if (tid < 256) {
            const float* wrp = WcS + rr * 136 + wv * 32;
            const float* wcp = WcS + ss * 136 + wv * 32;
            float m = 0.f;
#pragma unroll
            for (int k = 0; k < 32; k += 4) {
                float4 p = *(const float4*)&wrp[k];
                float4 q = *(const float4*)&wcp[k];
                m += p.x * q.x + p.y * q.y + p.z * q.z + p.w * q.w;
            }
            Mpart[wv * 64 + (tid & 63)] = m;
        }
        __syncthreads();
        if (tid < 64) {
            float m = (Mpart[tid] + Mpart[64 + tid]) + (Mpart[128 + tid] + Mpart[192 + tid]);
            int r8 = tid >> 3, s8 = tid & 7;
            float t = (r8 == s8) ? m : 0.f;
#pragma unroll
            for (int o = 1; o < 64; o <<= 1) t += __shfl_xor(t, o, 64);
            float eps = 1e-12f * t + 1e-35f;
            float v = m;
#pragma unroll
            for (int j = 0; j < 8; j++) {
                float dj = __shfl(v, j * 9, 64);
                dj = fmaxf(dj, eps);
                float lj = sqrtf(dj);
                float inv = 1.f / lj;
                if (s8 == j) v = (r8 == j) ? lj : (r8 > j ? v * inv : v);
                float Lr = __shfl(v, r8 * 8 + j, 64);
                float Ls = __shfl(v, s8 * 8 + j, 64);
                if (r8 > j && s8 > j) v -= Lr * Ls;
                if (tid == j) invdS[j] = inv;
            }
            LchS[tid] = v;
        }
        __syncthreads();
        // ---- backsolve V = W L^-T (tid<128) + fold V->bf16 convert
        if (tid < 128) {
            float w[8], vv[8];
#pragma unroll
            for (int s = 0; s < 8; s++) w[s] = WcS[s * 136 + tid];
#pragma unroll
            for (int s = 0; s < 8; s++) {
                float t2 = w[s];
                for (int j = 0; j < s; j++) t2 -= vv[j] * LchS[s * 8 + j];
                vv[s] = t2 * invdS[s];
                VcS[s * 136 + tid] = vv[s];
                unsigned short h = bf16rn(vv[s]);
                int boff = s * 256 + ((tid * 2) ^ ((s & 7) << 4));
                *(unsigned short*)((char*)VhB + boff) = h;
                *(unsigned short*)((char*)VlB + boff) = bf16rn(vv[s] - bf16tof(h));
            }
        }
        __syncthreads();
    }

    // ---- Rayleigh-Ritz: B = V^T W, K-split over waves 0..3
    if (tid < 256) {
        const float* vr = VcS + rr * 136 + wv * 32;
        const float* wcp = WcS + ss * 136 + wv * 32;
        float m = 0.f;
#pragma unroll
        for (int k = 0; k < 32; k += 4) {
            float4 p = *(const float4*)&vr[k];
            float4 q = *(const float4*)&wcp[k];
            m += p.x * q.x + p.y * q.y + p.z * q.z + p.w * q.w;
        }
        Mpart[wv * 64 + (tid & 63)] = m;
    }
    __syncthreads();
    if (tid < 64) {
        int r8 = tid >> 3, s8 = tid & 7;
        float m = (Mpart[tid] + Mpart[64 + tid]) + (Mpart[128 + tid] + Mpart[192 + tid]);
        float mT = __shfl(m, s8 * 8 + r8, 64);      // symmetrize via shuffle
        float b = 0.5f * (m + mT);
        float e = (r8 == s8) ? 1.f : 0.f;

        for (int sweep = 0; sweep < 6; sweep++) {
            for (int rd = 0; rd < 7; rd++) {
                int pr = (r8 == 7) ? rd : ((r8 == rd) ? 7 : (2 * rd + 7 - r8) % 7);
                int pc = (s8 == 7) ? rd : ((s8 == rd) ? 7 : (2 * rd + 7 - s8) % 7);
                int P = min(r8, pr), Q = max(r8, pr);
                int Pc = min(s8, pc), Qc = max(s8, pc);
                float app = __shfl(b, P * 9, 64);
                float aqq = __shfl(b, Q * 9, 64);
                float apq = __shfl(b, P * 8 + Q, 64);
                float cR, sR;
                if (fabsf(apq) < 1e-28f) { cR = 1.f; sR = 0.f; }
                else {
                    float tau = (aqq - app) / (2.f * apq);
                    float tt = ((tau >= 0.f) ? 1.f : -1.f) / (fabsf(tau) + sqrtf(1.f + tau * tau));
                    cR = rsqrtf(1.f + tt * tt); sR = tt * cR;
                }
                float ap2 = __shfl(b, Pc * 9, 64);
                float aq2 = __shfl(b, Qc * 9, 64);
                float apq2 = __shfl(b, Pc * 8 + Qc, 64);
                float cC, sC;
                if (fabsf(apq2) < 1e-28f) { cC = 1.f; sC = 0.f; }
                else {
                    float tau = (aq2 - ap2) / (2.f * apq2);
                    float tt = ((tau >= 0.f) ? 1.f : -1.f) / (fabsf(tau) + sqrtf(1.f + tau * tau));
                    cC = rsqrtf(1.f + tt * tt); sC = tt * cC;
                }
                float tv = __shfl(b, pr * 8 + s8, 64);
                float bn = (r8 < pr) ? (cR * b - sR * tv) : (sR * tv + cR * b);
                float t2 = __shfl(bn, r8 * 8 + pc, 64);
                b = (s8 < pc) ? (cC * bn - sC * t2) : (sC * t2 + cC * bn);
                float e2 = __shfl(e, r8 * 8 + pc, 64);
                e = (s8 < pc) ? (cC * e - sC * e2) : (sC * e2 + cC * e);
            }
        }
        B8S[tid] = b;
        E8S[tid] = e;
        if (tid == 0) {
            int used = 0;
            for (int r = 0; r < 3; r++) {
                int best = 0; float bv = -1e38f;
                for (int s = 0; s < 8; s++)
                    if (!(used & (1 << s)) && B8S[s * 9] > bv) { bv = B8S[s * 9]; best = s; }
                used |= 1 << best;
                idx3S[r] = best;
            }
        }
    }
    __syncthreads();

    // ---- U = V * E[:, idx3], warm-start save
    if (tid < 128) {
        float e[3][8];
#pragma unroll
        for (int r = 0; r < 3; r++)
#pragma unroll
            for (int s = 0; s < 8; s++) e[r][s] = E8S[s * 8 + idx3S[r]];
        float vcl[8];
#pragma unroll
        for (int s = 0; s < 8; s++) vcl[s] = VcS[s * 136 + tid];
#pragma unroll
        for (int r = 0; r < 3; r++) {
            float u = 0.f;
#pragma unroll
            for (int s = 0; s < 8; s++) u += vcl[s] * e[r][s];
            ws[U3_OFF + band * 384 + tid * 3 + r] = u;
        }
#pragma unroll
        for (int s = 0; s < 8; s++) ws[VW_OFF + band * 1024 + s * 128 + tid] = vcl[s];
    }
}

// ---------------- fused: utl = U^T L (phase 1) + UV/losses/L_new (phase 2) ----------------
// 2048 blocks (64-px chunks, 16 channel-subgroups) -> 8 blocks/CU grid headroom.
__global__ __launch_bounds__(256) void k_upd(const float* __restrict__ x,
                                             const float* __restrict__ W,
                                             const float* __restrict__ xg,
                                             float* __restrict__ out,
                                             float* __restrict__ ws,
                                             float alphapow, int writeUV, int titer) {
    int band = blockIdx.y, xc = blockIdx.x, tid = threadIdx.x;
    int w = tid >> 6, lane = tid & 63;
    int cs = tid >> 4;                 // 0..15 channel subgroup
    int p4 = (tid & 15) * 4;           // pixel within 64-px chunk
    int n0 = xc * 64;
    __shared__ float Us[128][4];
    __shared__ __align__(16) float up[48][68];   // partials [cs*3+r][px]
    __shared__ __align__(16) float um[3][68];    // reduced utl
    __shared__ float red[16];

    if (tid < 128) {
        Us[tid][0] = ws[U3_OFF + band * 384 + tid * 3 + 0];
        Us[tid][1] = ws[U3_OFF + band * 384 + tid * 3 + 1];
        Us[tid][2] = ws[U3_OFF + band * 384 + tid * 3 + 2];
    }
    __syncthreads();

    // ---- phase 1: utl[r][p] = sum_c U[c][r] * L[c][p]
    const float* Lb = ws + L_OFF + (size_t)band * CHN * NPIX;
    float4 a0 = make_float4(0.f,0.f,0.f,0.f), a1 = a0, a2 = a0;
#pragma unroll
    for (int cg = 0; cg < 8; cg++) {
        int c = cg * 16 + cs;
        float4 lv = *(const float4*)(Lb + (size_t)c * NPIX + n0 + p4);
        float u0 = Us[c][0], u1 = Us[c][1], u2 = Us[c][2];
        a0.x += u0 * lv.x; a0.y += u0 * lv.y; a0.z += u0 * lv.z; a0.w += u0 * lv.w;
        a1.x += u1 * lv.x; a1.y += u1 * lv.y; a1.z += u1 * lv.z; a1.w += u1 * lv.w;
        a2.x += u2 * lv.x; a2.y += u2 * lv.y; a2.z += u2 * lv.z; a2.w += u2 * lv.w;
    }
    *(float4*)&up[cs * 3 + 0][p4] = a0;
    *(float4*)&up[cs * 3 + 1][p4] = a1;
    *(float4*)&up[cs * 3 + 2][p4] = a2;
    __syncthreads();
    if (tid < 48) {
        int r = tid >> 4, pg = (tid & 15) * 4;
        float4 s = make_float4(0.f,0.f,0.f,0.f);
#pragma unroll
        for (int g = 0; g < 16; g++) {
            float4 u = *(float4*)&up[g * 3 + r][pg];
            s.x += u.x; s.y += u.y; s.z += u.z; s.w += u.w;
        }
        *(float4*)&um[r][pg] = s;
    }
    __syncthreads();

    // ---- phase 2: stream x/W/xg, compute UV, losses, L_new (and out at t=9)
    double sw = *(const double*)ws;
    float rho = 0.5f * (float)(sw / (double)NTOT) * alphapow;
    float4 t0 = *(float4*)&um[0][p4];
    float4 t1 = *(float4*)&um[1][p4];
    float4 t2 = *(float4*)&um[2][p4];
    float lf = 0.f, ll = 0.f;
    size_t base = (size_t)band * CHN * NPIX + n0 + p4;
    float* Lp = ws + L_OFF;
#pragma unroll
    for (int cg = 0; cg < 8; cg++) {
        int c = cg * 16 + cs;
        size_t idx = base + (size_t)c * NPIX;
        float4 xv = *(const float4*)(x + idx);
        float4 wv = *(const float4*)(W + idx);
        float4 gv = *(const float4*)(xg + idx);
        float u0 = Us[c][0], u1 = Us[c][1], u2 = Us[c][2];
        float4 uv, ln;
        uv.x = u0 * t0.x + u1 * t1.x + u2 * t2.x;
        uv.y = u0 * t0.y + u1 * t1.y + u2 * t2.y;
        uv.z = u0 * t0.z + u1 * t1.z + u2 * t2.z;
        uv.w = u0 * t0.w + u1 * t1.w + u2 * t2.w;
        float dx0 = uv.x - xv.x, dx1 = uv.y - xv.y, dx2 = uv.z - xv.z, dx3 = uv.w - xv.w;
        lf += wv.x * dx0 * dx0 + wv.y * dx1 * dx1 + wv.z * dx2 * dx2 + wv.w * dx3 * dx3;
        float g0 = uv.x - gv.x, g1 = uv.y - gv.y, g2 = uv.z - gv.z, g3 = uv.w - gv.w;
        ll += g0 * g0 + g1 * g1 + g2 * g2 + g3 * g3;
        ln.x = xv.x + (rho / (wv.x + rho)) * dx0;
        ln.y = xv.y + (rho / (wv.y + rho)) * dx1;
        ln.z = xv.z + (rho / (wv.z + rho)) * dx2;
        ln.w = xv.w + (rho / (wv.w + rho)) * dx3;
        *(float4*)(Lp + idx) = ln;
        if (writeUV) *(float4*)(out + idx) = uv;
    }
    for (int o = 32; o > 0; o >>= 1) { lf += __shfl_down(lf, o, 64); ll += __shfl_down(ll, o, 64); }
    if (lane == 0) { red[w] = lf; red[8 + w] = ll; }
    __syncthreads();
    if (tid == 0) {
        float a = red[0] + red[1] + red[2] + red[3];
        float b = red[8] + red[9] + red[10] + red[11];
        int bank = blockIdx.x & 7;
        atomicAdd((double*)ws + 24 + titer * 8 + bank,  (double)a);
        atomicAdd((double*)ws + 104 + titer * 8 + bank, (double)b);
    }
}

// ---------------- finalize losses ----------------
__global__ void k_final(float* __restrict__ out, const float* __restrict__ ws) {
    int tid = threadIdx.x;
    const double* d = (const double*)ws;
    if (tid < 10) {
        double s = 0.0;
        for (int k = 0; k < 8; k++) s += d[24 + tid * 8 + k];
        out[NTOT + tid] = (float)(s / (double)NTOT);
    } else if (tid < 20) {
        double s = 0.0;
        for (int k = 0; k < 8; k++) s += d[104 + (tid - 10) * 8 + k];
        out[NTOT + tid] = (float)(s / (double)NTOT);
    }
}

extern "C" void kernel_launch(void* const* d_in, const int* in_sizes, int n_in,
                              void* d_out, int out_size, void* d_ws, size_t ws_size,
                              hipStream_t stream) {
    const float* x  = (const float*)d_in[0];
    const float* W  = (const float*)d_in[1];
    const float* xg = (const float*)d_in[2];
    float* out = (float*)d_out;
    float* ws = (float*)d_ws;

    hipMemsetAsync(d_ws, 0, 4096, stream);   // zero scalar/accumulator block
    k_init<<<2048, 256, 0, stream>>>(x, W, ws);

    float ap = 1.0f;
    for (int t = 0; t < 10; t++) {
        k_gram<<<dim3(8, 32), 256, 0, stream>>>(ws);
        k_redG<<<256, 256, 0, stream>>>(ws);
        k_eig<<<32, 1024, 0, stream>>>(ws, t);
        k_upd<<<dim3(64, 32), 256, 0, stream>>>(x, W, xg, out, ws, ap, (t == 9) ? 1 : 0, t);
        ap *= 1.05f;
    }
    k_final<<<1, 64, 0, stream>>>(out, ws);
}